// Round 1
// baseline (341.107 us; speedup 1.0000x reference)
//
#include <hip/hip_runtime.h>
#include <stdint.h>

#define T_DIM 2048
#define D_DIM 1024
#define B_DIM 8
#define M_TOK (B_DIM * T_DIM)   // 16384 tokens
#define GAMMA_C 0.96875f

typedef float f32x4 __attribute__((ext_vector_type(4)));
typedef float fl4 __attribute__((ext_vector_type(4)));
typedef __bf16 bf16x8 __attribute__((ext_vector_type(8)));
typedef unsigned short us8 __attribute__((ext_vector_type(8)));
typedef unsigned short us4 __attribute__((ext_vector_type(4)));

// ---------- bf16 helpers (bit-level, no __bf16 arithmetic) ----------
__device__ __forceinline__ unsigned short f32_bf16_rne(float f) {
  uint32_t u = __builtin_bit_cast(uint32_t, f);
  return (unsigned short)((u + 0x7FFFu + ((u >> 16) & 1u)) >> 16);
}
__device__ __forceinline__ float bf16_f32(unsigned short h) {
  uint32_t u = ((uint32_t)h) << 16;
  return __builtin_bit_cast(float, u);
}

// ---------- global->LDS direct (CK-style addrspace casts) ----------
__device__ __forceinline__ void gload16(const void* g, void* l) {
  __builtin_amdgcn_global_load_lds(
      reinterpret_cast<const __attribute__((address_space(1))) uint32_t*>(
          reinterpret_cast<uintptr_t>(g)),
      reinterpret_cast<__attribute__((address_space(3))) uint32_t*>(
          reinterpret_cast<uintptr_t>(l)),
      16, 0, 0);
}

__device__ __forceinline__ bf16x8 ldfrag(const unsigned short* p) {
  us8 u = *reinterpret_cast<const us8*>(p);
  return __builtin_bit_cast(bf16x8, u);
}

// ---------- split f32 -> (hi, lo) bf16 ----------
__global__ __launch_bounds__(256) void k_split(const float* __restrict__ in, int n4,
                                               unsigned short* __restrict__ hi,
                                               unsigned short* __restrict__ lo) {
  int stride = gridDim.x * blockDim.x;
  for (int i = blockIdx.x * blockDim.x + threadIdx.x; i < n4; i += stride) {
    fl4 v = ((const fl4*)in)[i];
    us4 h, l;
#pragma unroll
    for (int j = 0; j < 4; ++j) {
      unsigned short hb = f32_bf16_rne(v[j]);
      float rem = v[j] - bf16_f32(hb);   // exact (Sterbenz)
      h[j] = hb;
      l[j] = f32_bf16_rne(rem);
    }
    ((us4*)hi)[i] = h;
    ((us4*)lo)[i] = l;
  }
}

// ---------- block reduction (256 threads = 4 waves) ----------
__device__ __forceinline__ float block_reduce_256(float s, float* red) {
#pragma unroll
  for (int m = 32; m >= 1; m >>= 1) s += __shfl_xor(s, m, 64);
  int w = threadIdx.x >> 6;
  if ((threadIdx.x & 63) == 0) red[w] = s;
  __syncthreads();
  return red[0] + red[1] + red[2] + red[3];
}

// u[t] = GAMMA * rowsum(W_ih[t,:]) + b_ih[t]
__global__ __launch_bounds__(256) void k_u(const float* __restrict__ Wih,
                                           const float* __restrict__ bih,
                                           float* __restrict__ u) {
  __shared__ float red[4];
  int t = blockIdx.x;
  const fl4* row = (const fl4*)(Wih + (size_t)t * T_DIM);
  float s = 0.f;
  for (int j = threadIdx.x; j < T_DIM / 4; j += 256) {
    fl4 v = row[j];
    s += v[0] + v[1] + v[2] + v[3];
  }
  float tot = block_reduce_256(s, red);
  if (threadIdx.x == 0) u[t] = GAMMA_C * tot + bih[t];
}

// h_out[t] = tanh(u[t] + dot(W_hh[t,:], h_prev) + bias_row[t])
__global__ __launch_bounds__(256) void k_step(const float* __restrict__ Whh,
                                              const float* __restrict__ hprev,
                                              const float* __restrict__ u,
                                              const float* __restrict__ biasrow,
                                              float* __restrict__ hout) {
  __shared__ float red[4];
  int t = blockIdx.x;
  const fl4* row = (const fl4*)(Whh + (size_t)t * T_DIM);
  const fl4* hp = (const fl4*)hprev;
  float s = 0.f;
  for (int j = threadIdx.x; j < T_DIM / 4; j += 256) {
    fl4 a = row[j], b = hp[j];
    s += a[0] * b[0] + a[1] * b[1] + a[2] * b[2] + a[3] * b[3];
  }
  float tot = block_reduce_256(s, red);
  if (threadIdx.x == 0) hout[t] = tanhf(u[t] + tot + biasrow[t]);
}

// =====================================================================
// Fused K,V split-GEMM + bias = rowdot(K,V).  BM=BN=128, BK=32,
// 512 thr = 8 waves (2m x 4n), per-wave 64x32 out (mi=4, ni=2).
// LDS double-buffered; T3-minimum 2-phase schedule.
// =====================================================================
__global__ __launch_bounds__(512) void k_kv_bias(
    const unsigned short* __restrict__ xh, const unsigned short* __restrict__ xl,
    const unsigned short* __restrict__ kh_, const unsigned short* __restrict__ kl_,
    const unsigned short* __restrict__ vh_, const unsigned short* __restrict__ vl_,
    float* __restrict__ bias) {
  __shared__ unsigned short sAh[2][128 * 32], sAl[2][128 * 32];
  __shared__ unsigned short sKh[2][128 * 32], sKl[2][128 * 32];
  __shared__ unsigned short sVh[2][128 * 32], sVl[2][128 * 32];

  const int tid = threadIdx.x;
  const int wave = tid >> 6;
  const int lane = tid & 63;
  const int wm = wave >> 2;   // 0..1
  const int wn = wave & 3;    // 0..3
  const int m0 = blockIdx.x * 128;
  const int n0 = blockIdx.y * 128;

  const int srow = tid >> 2;           // 0..127 (tile row staged by this thread)
  const int scol = (tid & 3) * 8;      // element offset within 32-elem row
  const size_t ga = (size_t)(m0 + srow) * D_DIM + scol;
  const size_t gb = (size_t)(n0 + srow) * D_DIM + scol;
  const int ldso = wave * 512;         // wave-uniform LDS base (ushort elems)

  f32x4 aK[4][2] = {};
  f32x4 aV[4][2] = {};

  const int arow0 = wm * 64 + (lane & 15);
  const int brow0 = wn * 32 + (lane & 15);
  const int kofs = (lane >> 4) * 8;

  // prologue: stage tile 0 into buffer 0
  {
    gload16(xh + ga, &sAh[0][ldso]);
    gload16(xl + ga, &sAl[0][ldso]);
    gload16(kh_ + gb, &sKh[0][ldso]);
    gload16(kl_ + gb, &sKl[0][ldso]);
    gload16(vh_ + gb, &sVh[0][ldso]);
    gload16(vl_ + gb, &sVl[0][ldso]);
  }
  __syncthreads();

  for (int kt = 0; kt < D_DIM / 32; ++kt) {
    const int cur = kt & 1;
    if (kt + 1 < D_DIM / 32) {       // prefetch next tile into other buffer
      const size_t ko = (size_t)(kt + 1) * 32;
      const int nb = cur ^ 1;
      gload16(xh + ga + ko, &sAh[nb][ldso]);
      gload16(xl + ga + ko, &sAl[nb][ldso]);
      gload16(kh_ + gb + ko, &sKh[nb][ldso]);
      gload16(kl_ + gb + ko, &sKl[nb][ldso]);
      gload16(vh_ + gb + ko, &sVh[nb][ldso]);
      gload16(vl_ + gb + ko, &sVl[nb][ldso]);
    }

    bf16x8 fah[4], fal[4], fkh[2], fkl[2], fvh[2], fvl[2];
#pragma unroll
    for (int mi = 0; mi < 4; ++mi) {
      int off = (arow0 + mi * 16) * 32 + kofs;
      fah[mi] = ldfrag(&sAh[cur][off]);
      fal[mi] = ldfrag(&sAl[cur][off]);
    }
#pragma unroll
    for (int ni = 0; ni < 2; ++ni) {
      int off = (brow0 + ni * 16) * 32 + kofs;
      fkh[ni] = ldfrag(&sKh[cur][off]);
      fkl[ni] = ldfrag(&sKl[cur][off]);
      fvh[ni] = ldfrag(&sVh[cur][off]);
      fvl[ni] = ldfrag(&sVl[cur][off]);
    }
#pragma unroll
    for (int mi = 0; mi < 4; ++mi)
#pragma unroll
      for (int ni = 0; ni < 2; ++ni) {
        aK[mi][ni] = __builtin_amdgcn_mfma_f32_16x16x32_bf16(fah[mi], fkh[ni], aK[mi][ni], 0, 0, 0);
        aK[mi][ni] = __builtin_amdgcn_mfma_f32_16x16x32_bf16(fah[mi], fkl[ni], aK[mi][ni], 0, 0, 0);
        aK[mi][ni] = __builtin_amdgcn_mfma_f32_16x16x32_bf16(fal[mi], fkh[ni], aK[mi][ni], 0, 0, 0);
        aV[mi][ni] = __builtin_amdgcn_mfma_f32_16x16x32_bf16(fah[mi], fvh[ni], aV[mi][ni], 0, 0, 0);
        aV[mi][ni] = __builtin_amdgcn_mfma_f32_16x16x32_bf16(fah[mi], fvl[ni], aV[mi][ni], 0, 0, 0);
        aV[mi][ni] = __builtin_amdgcn_mfma_f32_16x16x32_bf16(fal[mi], fvh[ni], aV[mi][ni], 0, 0, 0);
      }
    __syncthreads();  // drains prefetch vmem + frag lgkm; next iter may overwrite cur
  }

  // bias[row] += sum over this wave's 32 cols of K*V
#pragma unroll
  for (int mi = 0; mi < 4; ++mi)
#pragma unroll
    for (int j = 0; j < 4; ++j) {
      float s = aK[mi][0][j] * aV[mi][0][j] + aK[mi][1][j] * aV[mi][1][j];
      s += __shfl_xor(s, 1, 64);
      s += __shfl_xor(s, 2, 64);
      s += __shfl_xor(s, 4, 64);
      s += __shfl_xor(s, 8, 64);
      if ((lane & 15) == 0) {
        int row = m0 + wm * 64 + mi * 16 + (lane >> 4) * 4 + j;
        atomicAdd(&bias[row], s);
      }
    }
}

// =====================================================================
// Q split-GEMM with epilogue out[n,e] = S[n] * Q[n,e]
// =====================================================================
__global__ __launch_bounds__(512) void k_q_out(
    const unsigned short* __restrict__ xh, const unsigned short* __restrict__ xl,
    const unsigned short* __restrict__ qh_, const unsigned short* __restrict__ ql_,
    const float* __restrict__ S, float* __restrict__ out) {
  __shared__ unsigned short sAh[2][128 * 32], sAl[2][128 * 32];
  __shared__ unsigned short sBh[2][128 * 32], sBl[2][128 * 32];

  const int tid = threadIdx.x;
  const int wave = tid >> 6;
  const int lane = tid & 63;
  const int wm = wave >> 2;
  const int wn = wave & 3;
  const int m0 = blockIdx.x * 128;
  const int n0 = blockIdx.y * 128;

  const int srow = tid >> 2;
  const int scol = (tid & 3) * 8;
  const size_t ga = (size_t)(m0 + srow) * D_DIM + scol;
  const size_t gb = (size_t)(n0 + srow) * D_DIM + scol;
  const int ldso = wave * 512;

  f32x4 ac[4][2] = {};

  const int arow0 = wm * 64 + (lane & 15);
  const int brow0 = wn * 32 + (lane & 15);
  const int kofs = (lane >> 4) * 8;

  {
    gload16(xh + ga, &sAh[0][ldso]);
    gload16(xl + ga, &sAl[0][ldso]);
    gload16(qh_ + gb, &sBh[0][ldso]);
    gload16(ql_ + gb, &sBl[0][ldso]);
  }
  __syncthreads();

  for (int kt = 0; kt < D_DIM / 32; ++kt) {
    const int cur = kt & 1;
    if (kt + 1 < D_DIM / 32) {
      const size_t ko = (size_t)(kt + 1) * 32;
      const int nb = cur ^ 1;
      gload16(xh + ga + ko, &sAh[nb][ldso]);
      gload16(xl + ga + ko, &sAl[nb][ldso]);
      gload16(qh_ + gb + ko, &sBh[nb][ldso]);
      gload16(ql_ + gb + ko, &sBl[nb][ldso]);
    }

    bf16x8 fah[4], fal[4], fbh[2], fbl[2];
#pragma unroll
    for (int mi = 0; mi < 4; ++mi) {
      int off = (arow0 + mi * 16) * 32 + kofs;
      fah[mi] = ldfrag(&sAh[cur][off]);
      fal[mi] = ldfrag(&sAl[cur][off]);
    }
#pragma unroll
    for (int ni = 0; ni < 2; ++ni) {
      int off = (brow0 + ni * 16) * 32 + kofs;
      fbh[ni] = ldfrag(&sBh[cur][off]);
      fbl[ni] = ldfrag(&sBl[cur][off]);
    }
#pragma unroll
    for (int mi = 0; mi < 4; ++mi)
#pragma unroll
      for (int ni = 0; ni < 2; ++ni) {
        ac[mi][ni] = __builtin_amdgcn_mfma_f32_16x16x32_bf16(fah[mi], fbh[ni], ac[mi][ni], 0, 0, 0);
        ac[mi][ni] = __builtin_amdgcn_mfma_f32_16x16x32_bf16(fah[mi], fbl[ni], ac[mi][ni], 0, 0, 0);
        ac[mi][ni] = __builtin_amdgcn_mfma_f32_16x16x32_bf16(fal[mi], fbh[ni], ac[mi][ni], 0, 0, 0);
      }
    __syncthreads();
  }

  // epilogue: out = S[row] * acc
#pragma unroll
  for (int mi = 0; mi < 4; ++mi)
#pragma unroll
    for (int j = 0; j < 4; ++j) {
      int row = m0 + wm * 64 + mi * 16 + (lane >> 4) * 4 + j;
      float sc = S[row];
#pragma unroll
      for (int ni = 0; ni < 2; ++ni) {
        int col = n0 + wn * 32 + ni * 16 + (lane & 15);
        out[(size_t)row * D_DIM + col] = sc * ac[mi][ni][j];
      }
    }
}

// =====================================================================
extern "C" void kernel_launch(void* const* d_in, const int* in_sizes, int n_in,
                              void* d_out, int out_size, void* d_ws, size_t ws_size,
                              hipStream_t stream) {
  const float* x   = (const float*)d_in[0];
  const float* Wq  = (const float*)d_in[1];
  const float* Wk  = (const float*)d_in[2];
  const float* Wv  = (const float*)d_in[3];
  const float* Wih = (const float*)d_in[4];
  const float* Whh = (const float*)d_in[5];
  const float* bih = (const float*)d_in[6];
  float* out = (float*)d_out;

  char* ws = (char*)d_ws;
  size_t off = 0;
  auto alloc = [&](size_t bytes) -> char* {
    char* p = ws + off;
    off += (bytes + 255) & ~(size_t)255;
    return p;
  };
  unsigned short* xh  = (unsigned short*)alloc((size_t)M_TOK * D_DIM * 2);
  unsigned short* xl  = (unsigned short*)alloc((size_t)M_TOK * D_DIM * 2);
  unsigned short* wqh = (unsigned short*)alloc((size_t)D_DIM * D_DIM * 2);
  unsigned short* wql = (unsigned short*)alloc((size_t)D_DIM * D_DIM * 2);
  unsigned short* wkh = (unsigned short*)alloc((size_t)D_DIM * D_DIM * 2);
  unsigned short* wkl = (unsigned short*)alloc((size_t)D_DIM * D_DIM * 2);
  unsigned short* wvh = (unsigned short*)alloc((size_t)D_DIM * D_DIM * 2);
  unsigned short* wvl = (unsigned short*)alloc((size_t)D_DIM * D_DIM * 2);
  float* bias = (float*)alloc((size_t)M_TOK * 4);
  float* Sbuf = (float*)alloc((size_t)M_TOK * 4);
  float* ubuf = (float*)alloc((size_t)T_DIM * 4);
  float* zbuf = (float*)alloc((size_t)T_DIM * 4);
  (void)ws_size; (void)in_sizes; (void)n_in; (void)out_size;

  // 1. splits
  k_split<<<2048, 256, 0, stream>>>(x, M_TOK * D_DIM / 4, xh, xl);
  k_split<<<512, 256, 0, stream>>>(Wq, D_DIM * D_DIM / 4, wqh, wql);
  k_split<<<512, 256, 0, stream>>>(Wk, D_DIM * D_DIM / 4, wkh, wkl);
  k_split<<<512, 256, 0, stream>>>(Wv, D_DIM * D_DIM / 4, wvh, wvl);

  // 2. zero bias accumulator and h0
  hipMemsetAsync(bias, 0, (size_t)M_TOK * 4, stream);
  hipMemsetAsync(zbuf, 0, (size_t)T_DIM * 4, stream);

  // 3. u vector
  k_u<<<T_DIM, 256, 0, stream>>>(Wih, bih, ubuf);

  // 4. fused K,V GEMM -> bias
  k_kv_bias<<<dim3(128, 8), 512, 0, stream>>>(xh, xl, wkh, wkl, wvh, wvl, bias);

  // 5. 8-step tanh recurrence over batch rows
  for (int b = 0; b < B_DIM; ++b) {
    const float* hp = (b == 0) ? zbuf : (Sbuf + (size_t)(b - 1) * T_DIM);
    k_step<<<T_DIM, 256, 0, stream>>>(Whh, hp, ubuf, bias + (size_t)b * T_DIM,
                                      Sbuf + (size_t)b * T_DIM);
  }

  // 6. Q GEMM + scale-by-S epilogue
  k_q_out<<<dim3(128, 8), 512, 0, stream>>>(xh, xl, wqh, wql, Sbuf, out);
}

// Round 2
// 306.843 us; speedup vs baseline: 1.1117x; 1.1117x over previous
//
#include <hip/hip_runtime.h>
#include <stdint.h>

#define T_DIM 2048
#define D_DIM 1024
#define B_DIM 8
#define M_TOK (B_DIM * T_DIM)   // 16384 tokens
#define GAMMA_C 0.96875f

typedef float f32x4 __attribute__((ext_vector_type(4)));
typedef float fl4 __attribute__((ext_vector_type(4)));
typedef __bf16 bf16x8 __attribute__((ext_vector_type(8)));
typedef unsigned short us8 __attribute__((ext_vector_type(8)));
typedef unsigned short us4 __attribute__((ext_vector_type(4)));

// ---------- bf16 helpers ----------
__device__ __forceinline__ unsigned short f32_bf16_rne(float f) {
  uint32_t u = __builtin_bit_cast(uint32_t, f);
  return (unsigned short)((u + 0x7FFFu + ((u >> 16) & 1u)) >> 16);
}
__device__ __forceinline__ float bf16_f32(unsigned short h) {
  uint32_t u = ((uint32_t)h) << 16;
  return __builtin_bit_cast(float, u);
}

// ---------- global->LDS direct ----------
__device__ __forceinline__ void gload16(const void* g, void* l) {
  __builtin_amdgcn_global_load_lds(
      reinterpret_cast<const __attribute__((address_space(1))) uint32_t*>(
          reinterpret_cast<uintptr_t>(g)),
      reinterpret_cast<__attribute__((address_space(3))) uint32_t*>(
          reinterpret_cast<uintptr_t>(l)),
      16, 0, 0);
}

__device__ __forceinline__ bf16x8 ldfrag(const unsigned short* p) {
  us8 u = *reinterpret_cast<const us8*>(p);
  return __builtin_bit_cast(bf16x8, u);
}

// ---------- split f32 -> (hi, lo) bf16 ----------
__global__ __launch_bounds__(256) void k_split(const float* __restrict__ in, int n4,
                                               unsigned short* __restrict__ hi,
                                               unsigned short* __restrict__ lo) {
  int stride = gridDim.x * blockDim.x;
  for (int i = blockIdx.x * blockDim.x + threadIdx.x; i < n4; i += stride) {
    fl4 v = ((const fl4*)in)[i];
    us4 h, l;
#pragma unroll
    for (int j = 0; j < 4; ++j) {
      unsigned short hb = f32_bf16_rne(v[j]);
      float rem = v[j] - bf16_f32(hb);
      h[j] = hb;
      l[j] = f32_bf16_rne(rem);
    }
    ((us4*)hi)[i] = h;
    ((us4*)lo)[i] = l;
  }
}

// hi-only split (for Wq: plain bf16 is accurate enough on the Q path)
__global__ __launch_bounds__(256) void k_split_hi(const float* __restrict__ in, int n4,
                                                  unsigned short* __restrict__ hi) {
  int stride = gridDim.x * blockDim.x;
  for (int i = blockIdx.x * blockDim.x + threadIdx.x; i < n4; i += stride) {
    fl4 v = ((const fl4*)in)[i];
    us4 h;
#pragma unroll
    for (int j = 0; j < 4; ++j) h[j] = f32_bf16_rne(v[j]);
    ((us4*)hi)[i] = h;
  }
}

// ---------- u[t] = GAMMA * rowsum(W_ih[t,:]) + b_ih[t], one wave per row ----------
__global__ __launch_bounds__(256) void k_u(const float* __restrict__ Wih,
                                           const float* __restrict__ bih,
                                           float* __restrict__ u) {
  int wave = threadIdx.x >> 6, lane = threadIdx.x & 63;
  int t = blockIdx.x * 4 + wave;
  const fl4* row = (const fl4*)(Wih + (size_t)t * T_DIM);
  float s = 0.f;
#pragma unroll
  for (int i = 0; i < 8; ++i) {
    fl4 v = row[lane + i * 64];
    s += v[0] + v[1] + v[2] + v[3];
  }
#pragma unroll
  for (int m = 32; m >= 1; m >>= 1) s += __shfl_xor(s, m, 64);
  if (lane == 0) u[t] = GAMMA_C * s + bih[t];
}

// ---------- h_out[t] = tanh(u[t] + dot(W_hh[t,:], h_prev) + bias_row[t]) ----------
__global__ __launch_bounds__(256) void k_step(const float* __restrict__ Whh,
                                              const float* __restrict__ hprev,
                                              const float* __restrict__ u,
                                              const float* __restrict__ biasrow,
                                              float* __restrict__ hout) {
  int wave = threadIdx.x >> 6, lane = threadIdx.x & 63;
  int t = blockIdx.x * 4 + wave;
  const fl4* row = (const fl4*)(Whh + (size_t)t * T_DIM);
  const fl4* hp = (const fl4*)hprev;
  float s = 0.f;
#pragma unroll
  for (int i = 0; i < 8; ++i) {
    fl4 a = row[lane + i * 64];
    fl4 b = hp[lane + i * 64];
    s += a[0] * b[0] + a[1] * b[1] + a[2] * b[2] + a[3] * b[3];
  }
#pragma unroll
  for (int m = 32; m >= 1; m >>= 1) s += __shfl_xor(s, m, 64);
  if (lane == 0) hout[t] = tanhf(u[t] + s + biasrow[t]);
}

// XCD-ownership block mapping: bid -> (m_block 0..127, n_block 0..7).
// Default dispatch round-robins consecutive bids across the 8 XCDs, so give
// XCD x the m-strips [16x, 16x+16) for all n: A strip fetched by ONE XCD.
__device__ __forceinline__ void map_blk(int bid, int& mb, int& nb) {
  int xcd = bid & 7;
  int seq = bid >> 3;       // 0..127 within this XCD
  nb = seq & 7;             // n fastest: 8 consecutive same-XCD blocks share A strip
  mb = xcd * 16 + (seq >> 3);
}

// =====================================================================
// Fused K,V split-GEMM + bias = rowdot(K,V).  BM=BN=128, BK=32,
// 512 thr = 8 waves (2m x 4n), per-wave 64x32 out.
// 3-buffer pipeline, counted vmcnt (T3/T4), chunk-swizzled LDS (T2),
// setprio around MFMA (T5).
// =====================================================================
__global__ __launch_bounds__(512) void k_kv_bias(
    const unsigned short* __restrict__ xh, const unsigned short* __restrict__ xl,
    const unsigned short* __restrict__ kh_, const unsigned short* __restrict__ kl_,
    const unsigned short* __restrict__ vh_, const unsigned short* __restrict__ vl_,
    float* __restrict__ bias) {
  __shared__ unsigned short sAh[3][128 * 32], sAl[3][128 * 32];
  __shared__ unsigned short sKh[3][128 * 32], sKl[3][128 * 32];
  __shared__ unsigned short sVh[3][128 * 32], sVl[3][128 * 32];

  const int tid = threadIdx.x;
  const int wave = tid >> 6;
  const int lane = tid & 63;
  const int wm = wave >> 2;
  const int wn = wave & 3;
  int mb, nb;
  map_blk(blockIdx.x, mb, nb);
  const int m0 = mb * 128;
  const int n0 = nb * 128;

  // staging: thread tid owns row srow, LDS chunk (tid&3); source column is
  // swizzled so LDS(r, q) holds logical chunk q ^ ((r>>1)&3)  [2-way max]
  const int srow = tid >> 2;
  const int csrc = (tid & 3) ^ ((srow >> 1) & 3);
  const size_t ga = (size_t)(m0 + srow) * D_DIM + csrc * 8;
  const size_t gb = (size_t)(n0 + srow) * D_DIM + csrc * 8;
  const int ldst = tid * 8;  // ushort index of this thread's 16B slot

  f32x4 aK[4][2] = {};
  f32x4 aV[4][2] = {};

  const int c = lane >> 4;                       // logical 16B chunk 0..3
  const int arow = wm * 64 + (lane & 15);        // + mi*16 (swz invariant mod 16)
  const int aoff0 = arow * 32 + ((c ^ ((arow >> 1) & 3)) * 8);
  const int brow = wn * 32 + (lane & 15);
  const int boff0 = brow * 32 + ((c ^ ((brow >> 1) & 3)) * 8);

#define KV_STAGE(t, buf)                          \
  do {                                            \
    const size_t ko = (size_t)(t) * 32;           \
    gload16(xh + ga + ko, &sAh[buf][ldst]);       \
    gload16(xl + ga + ko, &sAl[buf][ldst]);       \
    gload16(kh_ + gb + ko, &sKh[buf][ldst]);      \
    gload16(kl_ + gb + ko, &sKl[buf][ldst]);      \
    gload16(vh_ + gb + ko, &sVh[buf][ldst]);      \
    gload16(vl_ + gb + ko, &sVl[buf][ldst]);      \
  } while (0)

#define KV_COMPUTE(buf)                                                              \
  do {                                                                               \
    bf16x8 fah[4], fal[4], fkh[2], fkl[2], fvh[2], fvl[2];                           \
    _Pragma("unroll") for (int mi = 0; mi < 4; ++mi) {                               \
      fah[mi] = ldfrag(&sAh[buf][aoff0 + mi * 512]);                                 \
      fal[mi] = ldfrag(&sAl[buf][aoff0 + mi * 512]);                                 \
    }                                                                                \
    _Pragma("unroll") for (int ni = 0; ni < 2; ++ni) {                               \
      fkh[ni] = ldfrag(&sKh[buf][boff0 + ni * 512]);                                 \
      fkl[ni] = ldfrag(&sKl[buf][boff0 + ni * 512]);                                 \
      fvh[ni] = ldfrag(&sVh[buf][boff0 + ni * 512]);                                 \
      fvl[ni] = ldfrag(&sVl[buf][boff0 + ni * 512]);                                 \
    }                                                                                \
    __builtin_amdgcn_s_setprio(1);                                                   \
    _Pragma("unroll") for (int mi = 0; mi < 4; ++mi)                                 \
        _Pragma("unroll") for (int ni = 0; ni < 2; ++ni) {                           \
      aK[mi][ni] = __builtin_amdgcn_mfma_f32_16x16x32_bf16(fah[mi], fkh[ni], aK[mi][ni], 0, 0, 0); \
      aK[mi][ni] = __builtin_amdgcn_mfma_f32_16x16x32_bf16(fah[mi], fkl[ni], aK[mi][ni], 0, 0, 0); \
      aK[mi][ni] = __builtin_amdgcn_mfma_f32_16x16x32_bf16(fal[mi], fkh[ni], aK[mi][ni], 0, 0, 0); \
      aV[mi][ni] = __builtin_amdgcn_mfma_f32_16x16x32_bf16(fah[mi], fvh[ni], aV[mi][ni], 0, 0, 0); \
      aV[mi][ni] = __builtin_amdgcn_mfma_f32_16x16x32_bf16(fah[mi], fvl[ni], aV[mi][ni], 0, 0, 0); \
      aV[mi][ni] = __builtin_amdgcn_mfma_f32_16x16x32_bf16(fal[mi], fvh[ni], aV[mi][ni], 0, 0, 0); \
    }                                                                                \
    __builtin_amdgcn_s_setprio(0);                                                   \
  } while (0)

  // prologue: 2 tiles in flight (12 loads/thread outstanding)
  KV_STAGE(0, 0);
  KV_STAGE(1, 1);

  int cur = 0, nx2 = 2;
  for (int kt = 0; kt < 30; ++kt) {
    asm volatile("s_waitcnt vmcnt(6)" ::: "memory");  // tile kt's 6 loads done
    __builtin_amdgcn_s_barrier();                     // all waves; prev-buf reads retired
    KV_STAGE(kt + 2, nx2);
    KV_COMPUTE(cur);
    cur = (cur == 2) ? 0 : cur + 1;
    nx2 = (nx2 == 2) ? 0 : nx2 + 1;
  }
  // kt = 30: tiles 30,31 outstanding
  asm volatile("s_waitcnt vmcnt(6)" ::: "memory");
  __builtin_amdgcn_s_barrier();
  KV_COMPUTE(cur);
  cur = (cur == 2) ? 0 : cur + 1;
  // kt = 31
  asm volatile("s_waitcnt vmcnt(0)" ::: "memory");
  __builtin_amdgcn_s_barrier();
  KV_COMPUTE(cur);

  // bias[row] += sum over this wave's 32 cols of K*V
#pragma unroll
  for (int mi = 0; mi < 4; ++mi)
#pragma unroll
    for (int j = 0; j < 4; ++j) {
      float s = aK[mi][0][j] * aV[mi][0][j] + aK[mi][1][j] * aV[mi][1][j];
      s += __shfl_xor(s, 1, 64);
      s += __shfl_xor(s, 2, 64);
      s += __shfl_xor(s, 4, 64);
      s += __shfl_xor(s, 8, 64);
      if ((lane & 15) == 0) {
        int row = m0 + wm * 64 + mi * 16 + (lane >> 4) * 4 + j;
        atomicAdd(&bias[row], s);
      }
    }
#undef KV_STAGE
#undef KV_COMPUTE
}

// =====================================================================
// Q plain-bf16 GEMM with epilogue out[n,e] = S[n] * Q[n,e]
// (error analysis: |S|<=1, bf16 Q err ~1.6e-3 sigma -> absmax ~0.009)
// =====================================================================
__global__ __launch_bounds__(512) void k_q_out(
    const unsigned short* __restrict__ xh,
    const unsigned short* __restrict__ qh_,
    const float* __restrict__ S, float* __restrict__ out) {
  __shared__ unsigned short sA[3][128 * 32];
  __shared__ unsigned short sB[3][128 * 32];

  const int tid = threadIdx.x;
  const int wave = tid >> 6;
  const int lane = tid & 63;
  const int wm = wave >> 2;
  const int wn = wave & 3;
  int mb, nb;
  map_blk(blockIdx.x, mb, nb);
  const int m0 = mb * 128;
  const int n0 = nb * 128;

  const int srow = tid >> 2;
  const int csrc = (tid & 3) ^ ((srow >> 1) & 3);
  const size_t ga = (size_t)(m0 + srow) * D_DIM + csrc * 8;
  const size_t gb = (size_t)(n0 + srow) * D_DIM + csrc * 8;
  const int ldst = tid * 8;

  f32x4 ac[4][2] = {};

  const int c = lane >> 4;
  const int arow = wm * 64 + (lane & 15);
  const int aoff0 = arow * 32 + ((c ^ ((arow >> 1) & 3)) * 8);
  const int brow = wn * 32 + (lane & 15);
  const int boff0 = brow * 32 + ((c ^ ((brow >> 1) & 3)) * 8);

#define Q_STAGE(t, buf)                          \
  do {                                           \
    const size_t ko = (size_t)(t) * 32;          \
    gload16(xh + ga + ko, &sA[buf][ldst]);       \
    gload16(qh_ + gb + ko, &sB[buf][ldst]);      \
  } while (0)

#define Q_COMPUTE(buf)                                                               \
  do {                                                                               \
    bf16x8 fa[4], fb[2];                                                             \
    _Pragma("unroll") for (int mi = 0; mi < 4; ++mi)                                 \
        fa[mi] = ldfrag(&sA[buf][aoff0 + mi * 512]);                                 \
    _Pragma("unroll") for (int ni = 0; ni < 2; ++ni)                                 \
        fb[ni] = ldfrag(&sB[buf][boff0 + ni * 512]);                                 \
    __builtin_amdgcn_s_setprio(1);                                                   \
    _Pragma("unroll") for (int mi = 0; mi < 4; ++mi)                                 \
        _Pragma("unroll") for (int ni = 0; ni < 2; ++ni)                             \
            ac[mi][ni] = __builtin_amdgcn_mfma_f32_16x16x32_bf16(fa[mi], fb[ni], ac[mi][ni], 0, 0, 0); \
    __builtin_amdgcn_s_setprio(0);                                                   \
  } while (0)

  Q_STAGE(0, 0);
  Q_STAGE(1, 1);

  int cur = 0, nx2 = 2;
  for (int kt = 0; kt < 30; ++kt) {
    asm volatile("s_waitcnt vmcnt(2)" ::: "memory");
    __builtin_amdgcn_s_barrier();
    Q_STAGE(kt + 2, nx2);
    Q_COMPUTE(cur);
    cur = (cur == 2) ? 0 : cur + 1;
    nx2 = (nx2 == 2) ? 0 : nx2 + 1;
  }
  asm volatile("s_waitcnt vmcnt(2)" ::: "memory");
  __builtin_amdgcn_s_barrier();
  Q_COMPUTE(cur);
  cur = (cur == 2) ? 0 : cur + 1;
  asm volatile("s_waitcnt vmcnt(0)" ::: "memory");
  __builtin_amdgcn_s_barrier();
  Q_COMPUTE(cur);

#pragma unroll
  for (int mi = 0; mi < 4; ++mi)
#pragma unroll
    for (int j = 0; j < 4; ++j) {
      int row = m0 + wm * 64 + mi * 16 + (lane >> 4) * 4 + j;
      float sc = S[row];
#pragma unroll
      for (int ni = 0; ni < 2; ++ni) {
        int col = n0 + wn * 32 + ni * 16 + (lane & 15);
        out[(size_t)row * D_DIM + col] = sc * ac[mi][ni][j];
      }
    }
#undef Q_STAGE
#undef Q_COMPUTE
}

// =====================================================================
extern "C" void kernel_launch(void* const* d_in, const int* in_sizes, int n_in,
                              void* d_out, int out_size, void* d_ws, size_t ws_size,
                              hipStream_t stream) {
  const float* x   = (const float*)d_in[0];
  const float* Wq  = (const float*)d_in[1];
  const float* Wk  = (const float*)d_in[2];
  const float* Wv  = (const float*)d_in[3];
  const float* Wih = (const float*)d_in[4];
  const float* Whh = (const float*)d_in[5];
  const float* bih = (const float*)d_in[6];
  float* out = (float*)d_out;

  char* ws = (char*)d_ws;
  size_t off = 0;
  auto alloc = [&](size_t bytes) -> char* {
    char* p = ws + off;
    off += (bytes + 255) & ~(size_t)255;
    return p;
  };
  unsigned short* xh  = (unsigned short*)alloc((size_t)M_TOK * D_DIM * 2);
  unsigned short* xl  = (unsigned short*)alloc((size_t)M_TOK * D_DIM * 2);
  unsigned short* wqh = (unsigned short*)alloc((size_t)D_DIM * D_DIM * 2);
  unsigned short* wkh = (unsigned short*)alloc((size_t)D_DIM * D_DIM * 2);
  unsigned short* wkl = (unsigned short*)alloc((size_t)D_DIM * D_DIM * 2);
  unsigned short* wvh = (unsigned short*)alloc((size_t)D_DIM * D_DIM * 2);
  unsigned short* wvl = (unsigned short*)alloc((size_t)D_DIM * D_DIM * 2);
  float* bias = (float*)alloc((size_t)M_TOK * 4);
  float* Sbuf = (float*)alloc((size_t)M_TOK * 4);
  float* ubuf = (float*)alloc((size_t)T_DIM * 4);
  float* zbuf = (float*)alloc((size_t)T_DIM * 4);
  (void)ws_size; (void)in_sizes; (void)n_in; (void)out_size;

  // 1. splits
  k_split<<<2048, 256, 0, stream>>>(x, M_TOK * D_DIM / 4, xh, xl);
  k_split_hi<<<512, 256, 0, stream>>>(Wq, D_DIM * D_DIM / 4, wqh);
  k_split<<<512, 256, 0, stream>>>(Wk, D_DIM * D_DIM / 4, wkh, wkl);
  k_split<<<512, 256, 0, stream>>>(Wv, D_DIM * D_DIM / 4, wvh, wvl);

  // 2. zero bias accumulator and h0
  hipMemsetAsync(bias, 0, (size_t)M_TOK * 4, stream);
  hipMemsetAsync(zbuf, 0, (size_t)T_DIM * 4, stream);

  // 3. u vector (wave per row)
  k_u<<<T_DIM / 4, 256, 0, stream>>>(Wih, bih, ubuf);

  // 4. fused K,V GEMM -> bias
  k_kv_bias<<<1024, 512, 0, stream>>>(xh, xl, wkh, wkl, wvh, wvl, bias);

  // 5. 8-step tanh recurrence over batch rows (wave per row)
  for (int b = 0; b < B_DIM; ++b) {
    const float* hp = (b == 0) ? zbuf : (Sbuf + (size_t)(b - 1) * T_DIM);
    k_step<<<T_DIM / 4, 256, 0, stream>>>(Whh, hp, ubuf, bias + (size_t)b * T_DIM,
                                          Sbuf + (size_t)b * T_DIM);
  }

  // 6. Q GEMM + scale-by-S epilogue
  k_q_out<<<1024, 512, 0, stream>>>(xh, wqh, Sbuf, out);
}

// Round 3
// 272.033 us; speedup vs baseline: 1.2539x; 1.1280x over previous
//
#include <hip/hip_runtime.h>
#include <stdint.h>

#define T_DIM 2048
#define D_DIM 1024
#define B_DIM 8
#define M_TOK (B_DIM * T_DIM)   // 16384 tokens
#define GAMMA_C 0.96875f

typedef float f32x4 __attribute__((ext_vector_type(4)));
typedef float f32x16 __attribute__((ext_vector_type(16)));
typedef float fl4 __attribute__((ext_vector_type(4)));
typedef __bf16 bf16x8 __attribute__((ext_vector_type(8)));
typedef unsigned short us8 __attribute__((ext_vector_type(8)));
typedef unsigned short us4 __attribute__((ext_vector_type(4)));

// ---------- bf16 helpers ----------
__device__ __forceinline__ unsigned short f32_bf16_rne(float f) {
  uint32_t u = __builtin_bit_cast(uint32_t, f);
  return (unsigned short)((u + 0x7FFFu + ((u >> 16) & 1u)) >> 16);
}
__device__ __forceinline__ float bf16_f32(unsigned short h) {
  uint32_t u = ((uint32_t)h) << 16;
  return __builtin_bit_cast(float, u);
}

// ---------- global->LDS direct ----------
__device__ __forceinline__ void gload16(const void* g, void* l) {
  __builtin_amdgcn_global_load_lds(
      reinterpret_cast<const __attribute__((address_space(1))) uint32_t*>(
          reinterpret_cast<uintptr_t>(g)),
      reinterpret_cast<__attribute__((address_space(3))) uint32_t*>(
          reinterpret_cast<uintptr_t>(l)),
      16, 0, 0);
}

__device__ __forceinline__ bf16x8 ldfrag(const unsigned short* p) {
  us8 u = *reinterpret_cast<const us8*>(p);
  return __builtin_bit_cast(bf16x8, u);
}

// ---------- split f32 -> (hi, lo) bf16 ----------
__global__ __launch_bounds__(256) void k_split(const float* __restrict__ in, int n4,
                                               unsigned short* __restrict__ hi,
                                               unsigned short* __restrict__ lo) {
  int stride = gridDim.x * blockDim.x;
  for (int i = blockIdx.x * blockDim.x + threadIdx.x; i < n4; i += stride) {
    fl4 v = ((const fl4*)in)[i];
    us4 h, l;
#pragma unroll
    for (int j = 0; j < 4; ++j) {
      unsigned short hb = f32_bf16_rne(v[j]);
      float rem = v[j] - bf16_f32(hb);
      h[j] = hb;
      l[j] = f32_bf16_rne(rem);
    }
    ((us4*)hi)[i] = h;
    ((us4*)lo)[i] = l;
  }
}

__global__ __launch_bounds__(256) void k_split_hi(const float* __restrict__ in, int n4,
                                                  unsigned short* __restrict__ hi) {
  int stride = gridDim.x * blockDim.x;
  for (int i = blockIdx.x * blockDim.x + threadIdx.x; i < n4; i += stride) {
    fl4 v = ((const fl4*)in)[i];
    us4 h;
#pragma unroll
    for (int j = 0; j < 4; ++j) h[j] = f32_bf16_rne(v[j]);
    ((us4*)hi)[i] = h;
  }
}

// ---------- transpose-split: out_t[d][e] = split(in[e][d]), 64x64 tiles ----------
__global__ __launch_bounds__(256) void k_split_T(const float* __restrict__ in,
                                                 unsigned short* __restrict__ th,
                                                 unsigned short* __restrict__ tl) {
  __shared__ float tile[64][69];
  int be = blockIdx.x >> 4, bd = blockIdx.x & 15;
  int e0 = be * 64, d0 = bd * 64;
  int r = threadIdx.x >> 4;
  int c = (threadIdx.x & 15) * 4;
#pragma unroll
  for (int it = 0; it < 4; ++it) {
    int rr = r + it * 16;
    fl4 v = *(const fl4*)(in + (size_t)(e0 + rr) * D_DIM + d0 + c);
#pragma unroll
    for (int j = 0; j < 4; ++j) tile[rr][c + j] = v[j];
  }
  __syncthreads();
#pragma unroll
  for (int it = 0; it < 4; ++it) {
    int dr = r + it * 16;
    us4 h, l;
#pragma unroll
    for (int j = 0; j < 4; ++j) {
      float f = tile[c + j][dr];
      h[j] = f32_bf16_rne(f);
      l[j] = f32_bf16_rne(f - bf16_f32(h[j]));
    }
    *(us4*)(th + (size_t)(d0 + dr) * D_DIM + e0 + c) = h;
    *(us4*)(tl + (size_t)(d0 + dr) * D_DIM + e0 + c) = l;
  }
}

// ---------- u[t] = GAMMA * rowsum(W_ih[t,:]) + b_ih[t], one wave per row ----------
__global__ __launch_bounds__(256) void k_u(const float* __restrict__ Wih,
                                           const float* __restrict__ bih,
                                           float* __restrict__ u) {
  int wave = threadIdx.x >> 6, lane = threadIdx.x & 63;
  int t = blockIdx.x * 4 + wave;
  const fl4* row = (const fl4*)(Wih + (size_t)t * T_DIM);
  float s = 0.f;
#pragma unroll
  for (int i = 0; i < 8; ++i) {
    fl4 v = row[lane + i * 64];
    s += v[0] + v[1] + v[2] + v[3];
  }
#pragma unroll
  for (int m = 32; m >= 1; m >>= 1) s += __shfl_xor(s, m, 64);
  if (lane == 0) u[t] = GAMMA_C * s + bih[t];
}

// ---------- h_out[t] = tanh(u[t] + dot(Whh_bf16[t,:], h_prev) + bias_row[t]) ----------
__global__ __launch_bounds__(256) void k_step_bf(const unsigned short* __restrict__ Whh_b,
                                                 const float* __restrict__ hprev,
                                                 const float* __restrict__ u,
                                                 const float* __restrict__ biasrow,
                                                 float* __restrict__ hout) {
  int wave = threadIdx.x >> 6, lane = threadIdx.x & 63;
  int t = blockIdx.x * 4 + wave;
  const unsigned short* row = Whh_b + (size_t)t * T_DIM;
  float s = 0.f;
#pragma unroll
  for (int i = 0; i < 4; ++i) {
    us8 w = *(const us8*)(row + i * 512 + lane * 8);
    fl4 h0 = *(const fl4*)(hprev + i * 512 + lane * 8);
    fl4 h1 = *(const fl4*)(hprev + i * 512 + lane * 8 + 4);
    s += bf16_f32(w[0]) * h0[0] + bf16_f32(w[1]) * h0[1] +
         bf16_f32(w[2]) * h0[2] + bf16_f32(w[3]) * h0[3] +
         bf16_f32(w[4]) * h1[0] + bf16_f32(w[5]) * h1[1] +
         bf16_f32(w[6]) * h1[2] + bf16_f32(w[7]) * h1[3];
  }
#pragma unroll
  for (int m = 32; m >= 1; m >>= 1) s += __shfl_xor(s, m, 64);
  if (lane == 0) hout[t] = tanhf(u[t] + s + biasrow[t]);
}

// XCD-chunked block mapping for 1024-block GEMM grids (128 mb x 8 nb)
__device__ __forceinline__ void map_blk(int bid, int& mb, int& nb) {
  int sw = (bid & 7) * 128 + (bid >> 3);
  mb = sw >> 3;
  nb = sw & 7;
}

// =====================================================================
// Ht[d'][d] = sum_e Wv[e,d'] * Wk[e,d], 3-term split, epilogue re-split.
// A = wvt (hi/lo, [d'][e] row-major), B = wkt (hi/lo, [d][e] row-major).
// 64x64 tiles, 256 blocks, 4 waves (2x2), per-wave one 32x32, MFMA 32x32x16.
// =====================================================================
__global__ __launch_bounds__(256) void k_ht(
    const unsigned short* __restrict__ ah, const unsigned short* __restrict__ al,
    const unsigned short* __restrict__ bh, const unsigned short* __restrict__ bl,
    unsigned short* __restrict__ outh, unsigned short* __restrict__ outl) {
  __shared__ unsigned short sAh[2][64 * 32], sAl[2][64 * 32];
  __shared__ unsigned short sBh[2][64 * 32], sBl[2][64 * 32];
  const int tid = threadIdx.x;
  const int wave = tid >> 6, lane = tid & 63;
  const int wm = wave >> 1, wn = wave & 1;
  const int m0 = (blockIdx.x >> 4) * 64, n0 = (blockIdx.x & 15) * 64;
  const int hi32 = lane >> 5;

  const int srow = tid >> 2;
  const int csrc = (tid & 3) ^ ((srow >> 1) & 3);
  const size_t ga = (size_t)(m0 + srow) * D_DIM + csrc * 8;
  const size_t gb = (size_t)(n0 + srow) * D_DIM + csrc * 8;
  const int ldst = tid * 8;

  f32x16 acc = {};
  const int ar = wm * 32 + (lane & 31);
  const int br = wn * 32 + (lane & 31);
  int aoff[2], boff[2];
#pragma unroll
  for (int kh = 0; kh < 2; ++kh) {
    aoff[kh] = ar * 32 + (((kh * 2 + hi32) ^ ((ar >> 1) & 3)) * 8);
    boff[kh] = br * 32 + (((kh * 2 + hi32) ^ ((br >> 1) & 3)) * 8);
  }

#define HT_STAGE(t, buf)                         \
  do {                                           \
    const size_t ko = (size_t)(t) * 32;          \
    gload16(ah + ga + ko, &sAh[buf][ldst]);      \
    gload16(al + ga + ko, &sAl[buf][ldst]);      \
    gload16(bh + gb + ko, &sBh[buf][ldst]);      \
    gload16(bl + gb + ko, &sBl[buf][ldst]);      \
  } while (0)

  HT_STAGE(0, 0);
  __syncthreads();
  for (int kt = 0; kt < 32; ++kt) {
    const int cur = kt & 1;
    if (kt < 31) HT_STAGE(kt + 1, cur ^ 1);
#pragma unroll
    for (int kh = 0; kh < 2; ++kh) {
      bf16x8 fah = ldfrag(&sAh[cur][aoff[kh]]);
      bf16x8 fal = ldfrag(&sAl[cur][aoff[kh]]);
      bf16x8 fbh = ldfrag(&sBh[cur][boff[kh]]);
      bf16x8 fbl = ldfrag(&sBl[cur][boff[kh]]);
      acc = __builtin_amdgcn_mfma_f32_32x32x16_bf16(fah, fbh, acc, 0, 0, 0);
      acc = __builtin_amdgcn_mfma_f32_32x32x16_bf16(fah, fbl, acc, 0, 0, 0);
      acc = __builtin_amdgcn_mfma_f32_32x32x16_bf16(fal, fbh, acc, 0, 0, 0);
    }
    __syncthreads();
  }
#pragma unroll
  for (int r = 0; r < 16; ++r) {
    int row = m0 + wm * 32 + (r & 3) + 8 * (r >> 2) + 4 * hi32;
    int col = n0 + wn * 32 + (lane & 31);
    float f = acc[r];
    unsigned short hb = f32_bf16_rne(f);
    unsigned short lb = f32_bf16_rne(f - bf16_f32(hb));
    size_t ad = (size_t)row * D_DIM + col;
    outh[ad] = hb;
    outl[ad] = lb;
  }
#undef HT_STAGE
}

// =====================================================================
// Y = x.Ht^T fused bias: bias[t] += sum_{d' in block} x[t,d'] * Y[t,d'].
// A = xh/xl, B = Hth/Htl ([d'][d] row-major). 3-term split.
// BM=BN=128, BK=32, 8 waves (2m x 4n), per-wave 64x32, MFMA 32x32x16.
// LDS 64KB -> 2 blocks/CU (4 waves/SIMD) with launch_bounds(512,4).
// =====================================================================
__global__ __launch_bounds__(512, 4) void k_y_bias(
    const unsigned short* __restrict__ xh, const unsigned short* __restrict__ xl,
    const unsigned short* __restrict__ bh, const unsigned short* __restrict__ bl,
    const float* __restrict__ xf, float* __restrict__ bias) {
  __shared__ unsigned short sAh[2][128 * 32], sAl[2][128 * 32];
  __shared__ unsigned short sBh[2][128 * 32], sBl[2][128 * 32];
  const int tid = threadIdx.x;
  const int wave = tid >> 6, lane = tid & 63;
  const int wm = wave >> 2, wn = wave & 3;
  int mb, nb;
  map_blk(blockIdx.x, mb, nb);
  const int m0 = mb * 128, n0 = nb * 128;
  const int hi32 = lane >> 5;

  const int srow = tid >> 2;
  const int csrc = (tid & 3) ^ ((srow >> 1) & 3);
  const size_t ga = (size_t)(m0 + srow) * D_DIM + csrc * 8;
  const size_t gb = (size_t)(n0 + srow) * D_DIM + csrc * 8;
  const int ldst = tid * 8;

  f32x16 acc[2] = {};
  int aoff[2][2], boff[2];
#pragma unroll
  for (int mi = 0; mi < 2; ++mi) {
    int r = wm * 64 + mi * 32 + (lane & 31);
#pragma unroll
    for (int kh = 0; kh < 2; ++kh)
      aoff[mi][kh] = r * 32 + (((kh * 2 + hi32) ^ ((r >> 1) & 3)) * 8);
  }
  {
    int r = wn * 32 + (lane & 31);
#pragma unroll
    for (int kh = 0; kh < 2; ++kh)
      boff[kh] = r * 32 + (((kh * 2 + hi32) ^ ((r >> 1) & 3)) * 8);
  }

#define Y_STAGE(t, buf)                          \
  do {                                           \
    const size_t ko = (size_t)(t) * 32;          \
    gload16(xh + ga + ko, &sAh[buf][ldst]);      \
    gload16(xl + ga + ko, &sAl[buf][ldst]);      \
    gload16(bh + gb + ko, &sBh[buf][ldst]);      \
    gload16(bl + gb + ko, &sBl[buf][ldst]);      \
  } while (0)

  Y_STAGE(0, 0);
  __syncthreads();
  for (int kt = 0; kt < 32; ++kt) {
    const int cur = kt & 1;
    if (kt < 31) Y_STAGE(kt + 1, cur ^ 1);
#pragma unroll
    for (int kh = 0; kh < 2; ++kh) {
      bf16x8 fa0h = ldfrag(&sAh[cur][aoff[0][kh]]);
      bf16x8 fa0l = ldfrag(&sAl[cur][aoff[0][kh]]);
      bf16x8 fa1h = ldfrag(&sAh[cur][aoff[1][kh]]);
      bf16x8 fa1l = ldfrag(&sAl[cur][aoff[1][kh]]);
      bf16x8 fbh_ = ldfrag(&sBh[cur][boff[kh]]);
      bf16x8 fbl_ = ldfrag(&sBl[cur][boff[kh]]);
      __builtin_amdgcn_s_setprio(1);
      acc[0] = __builtin_amdgcn_mfma_f32_32x32x16_bf16(fa0h, fbh_, acc[0], 0, 0, 0);
      acc[0] = __builtin_amdgcn_mfma_f32_32x32x16_bf16(fa0h, fbl_, acc[0], 0, 0, 0);
      acc[0] = __builtin_amdgcn_mfma_f32_32x32x16_bf16(fa0l, fbh_, acc[0], 0, 0, 0);
      acc[1] = __builtin_amdgcn_mfma_f32_32x32x16_bf16(fa1h, fbh_, acc[1], 0, 0, 0);
      acc[1] = __builtin_amdgcn_mfma_f32_32x32x16_bf16(fa1h, fbl_, acc[1], 0, 0, 0);
      acc[1] = __builtin_amdgcn_mfma_f32_32x32x16_bf16(fa1l, fbh_, acc[1], 0, 0, 0);
      __builtin_amdgcn_s_setprio(0);
    }
    __syncthreads();
  }

  // bias fold: p = x[row,col] * Y_acc, reduce over the 32 cols, atomicAdd.
#pragma unroll
  for (int mi = 0; mi < 2; ++mi)
#pragma unroll
    for (int r = 0; r < 16; ++r) {
      int row = m0 + wm * 64 + mi * 32 + (r & 3) + 8 * (r >> 2) + 4 * hi32;
      int col = n0 + wn * 32 + (lane & 31);
      float p = xf[(size_t)row * D_DIM + col] * acc[mi][r];
      p += __shfl_xor(p, 1, 64);
      p += __shfl_xor(p, 2, 64);
      p += __shfl_xor(p, 4, 64);
      p += __shfl_xor(p, 8, 64);
      p += __shfl_xor(p, 16, 64);
      if ((lane & 31) == 0) atomicAdd(&bias[row], p);
    }
#undef Y_STAGE
}

// =====================================================================
// Q plain-bf16 GEMM with epilogue out[t,e] = S[t] * Q[t,e].
// BM=BN=128, BK=32, 8 waves, per-wave 64x32, MFMA 32x32x16. LDS 32KB.
// =====================================================================
__global__ __launch_bounds__(512, 4) void k_q_out(
    const unsigned short* __restrict__ xh,
    const unsigned short* __restrict__ qh_,
    const float* __restrict__ S, float* __restrict__ out) {
  __shared__ unsigned short sA[2][128 * 32];
  __shared__ unsigned short sB[2][128 * 32];
  const int tid = threadIdx.x;
  const int wave = tid >> 6, lane = tid & 63;
  const int wm = wave >> 2, wn = wave & 3;
  int mb, nb;
  map_blk(blockIdx.x, mb, nb);
  const int m0 = mb * 128, n0 = nb * 128;
  const int hi32 = lane >> 5;

  const int srow = tid >> 2;
  const int csrc = (tid & 3) ^ ((srow >> 1) & 3);
  const size_t ga = (size_t)(m0 + srow) * D_DIM + csrc * 8;
  const size_t gb = (size_t)(n0 + srow) * D_DIM + csrc * 8;
  const int ldst = tid * 8;

  f32x16 acc[2] = {};
  int aoff[2][2], boff[2];
#pragma unroll
  for (int mi = 0; mi < 2; ++mi) {
    int r = wm * 64 + mi * 32 + (lane & 31);
#pragma unroll
    for (int kh = 0; kh < 2; ++kh)
      aoff[mi][kh] = r * 32 + (((kh * 2 + hi32) ^ ((r >> 1) & 3)) * 8);
  }
  {
    int r = wn * 32 + (lane & 31);
#pragma unroll
    for (int kh = 0; kh < 2; ++kh)
      boff[kh] = r * 32 + (((kh * 2 + hi32) ^ ((r >> 1) & 3)) * 8);
  }

#define Q_STAGE(t, buf)                          \
  do {                                           \
    const size_t ko = (size_t)(t) * 32;          \
    gload16(xh + ga + ko, &sA[buf][ldst]);       \
    gload16(qh_ + gb + ko, &sB[buf][ldst]);      \
  } while (0)

  Q_STAGE(0, 0);
  __syncthreads();
  for (int kt = 0; kt < 32; ++kt) {
    const int cur = kt & 1;
    if (kt < 31) Q_STAGE(kt + 1, cur ^ 1);
#pragma unroll
    for (int kh = 0; kh < 2; ++kh) {
      bf16x8 fa0 = ldfrag(&sA[cur][aoff[0][kh]]);
      bf16x8 fa1 = ldfrag(&sA[cur][aoff[1][kh]]);
      bf16x8 fb = ldfrag(&sB[cur][boff[kh]]);
      __builtin_amdgcn_s_setprio(1);
      acc[0] = __builtin_amdgcn_mfma_f32_32x32x16_bf16(fa0, fb, acc[0], 0, 0, 0);
      acc[1] = __builtin_amdgcn_mfma_f32_32x32x16_bf16(fa1, fb, acc[1], 0, 0, 0);
      __builtin_amdgcn_s_setprio(0);
    }
    __syncthreads();
  }

#pragma unroll
  for (int mi = 0; mi < 2; ++mi)
#pragma unroll
    for (int r = 0; r < 16; ++r) {
      int row = m0 + wm * 64 + mi * 32 + (r & 3) + 8 * (r >> 2) + 4 * hi32;
      int col = n0 + wn * 32 + (lane & 31);
      out[(size_t)row * D_DIM + col] = S[row] * acc[mi][r];
    }
#undef Q_STAGE
}

// =====================================================================
extern "C" void kernel_launch(void* const* d_in, const int* in_sizes, int n_in,
                              void* d_out, int out_size, void* d_ws, size_t ws_size,
                              hipStream_t stream) {
  const float* x   = (const float*)d_in[0];
  const float* Wq  = (const float*)d_in[1];
  const float* Wk  = (const float*)d_in[2];
  const float* Wv  = (const float*)d_in[3];
  const float* Wih = (const float*)d_in[4];
  const float* Whh = (const float*)d_in[5];
  const float* bih = (const float*)d_in[6];
  float* out = (float*)d_out;

  char* ws = (char*)d_ws;
  size_t off = 0;
  auto alloc = [&](size_t bytes) -> char* {
    char* p = ws + off;
    off += (bytes + 255) & ~(size_t)255;
    return p;
  };
  unsigned short* xh   = (unsigned short*)alloc((size_t)M_TOK * D_DIM * 2);
  unsigned short* xl   = (unsigned short*)alloc((size_t)M_TOK * D_DIM * 2);
  unsigned short* wqh  = (unsigned short*)alloc((size_t)D_DIM * D_DIM * 2);
  unsigned short* wkth = (unsigned short*)alloc((size_t)D_DIM * D_DIM * 2);
  unsigned short* wktl = (unsigned short*)alloc((size_t)D_DIM * D_DIM * 2);
  unsigned short* wvth = (unsigned short*)alloc((size_t)D_DIM * D_DIM * 2);
  unsigned short* wvtl = (unsigned short*)alloc((size_t)D_DIM * D_DIM * 2);
  unsigned short* hth  = (unsigned short*)alloc((size_t)D_DIM * D_DIM * 2);
  unsigned short* htl  = (unsigned short*)alloc((size_t)D_DIM * D_DIM * 2);
  float* bias = (float*)alloc((size_t)M_TOK * 4);
  float* Sbuf = (float*)alloc((size_t)M_TOK * 4);
  float* ubuf = (float*)alloc((size_t)T_DIM * 4);
  float* zbuf = (float*)alloc((size_t)T_DIM * 4);
  // Whh bf16 (8 MB) aliases wkth..wvtl (4 x 2 MB, dead after k_ht).
  unsigned short* whhb = wkth;
  (void)ws_size; (void)in_sizes; (void)n_in; (void)out_size;

  // 1. splits
  k_split<<<2048, 256, 0, stream>>>(x, M_TOK * D_DIM / 4, xh, xl);
  k_split_hi<<<512, 256, 0, stream>>>(Wq, D_DIM * D_DIM / 4, wqh);
  k_split_T<<<256, 256, 0, stream>>>(Wk, wkth, wktl);
  k_split_T<<<256, 256, 0, stream>>>(Wv, wvth, wvtl);

  // 2. zero bias accumulator and h0
  hipMemsetAsync(bias, 0, (size_t)M_TOK * 4, stream);
  hipMemsetAsync(zbuf, 0, (size_t)T_DIM * 4, stream);

  // 3. u vector
  k_u<<<T_DIM / 4, 256, 0, stream>>>(Wih, bih, ubuf);

  // 4. Ht[d'][d] = sum_e Wv[e,d'] Wk[e,d]  (A=wvt, B=wkt)
  k_ht<<<256, 256, 0, stream>>>(wvth, wvtl, wkth, wktl, hth, htl);

  // 5. Whh -> bf16 (after k_ht: aliases the transposed weight splits)
  k_split_hi<<<1024, 256, 0, stream>>>(Whh, T_DIM * T_DIM / 4, whhb);

  // 6. Y = x.Ht fused into bias = rowdot(x, Y)
  k_y_bias<<<1024, 512, 0, stream>>>(xh, xl, hth, htl, x, bias);

  // 7. 8-step tanh recurrence over batch rows (wave per row)
  for (int b = 0; b < B_DIM; ++b) {
    const float* hp = (b == 0) ? zbuf : (Sbuf + (size_t)(b - 1) * T_DIM);
    k_step_bf<<<T_DIM / 4, 256, 0, stream>>>(whhb, hp, ubuf, bias + (size_t)b * T_DIM,
                                             Sbuf + (size_t)b * T_DIM);
  }

  // 8. Q GEMM + scale-by-S epilogue
  k_q_out<<<1024, 512, 0, stream>>>(xh, wqh, Sbuf, out);
}

// Round 4
// 267.249 us; speedup vs baseline: 1.2764x; 1.0179x over previous
//
#include <hip/hip_runtime.h>
#include <stdint.h>

#define T_DIM 2048
#define D_DIM 1024
#define B_DIM 8
#define M_TOK (B_DIM * T_DIM)   // 16384 tokens
#define GAMMA_C 0.96875f

typedef float f32x4 __attribute__((ext_vector_type(4)));
typedef float f32x16 __attribute__((ext_vector_type(16)));
typedef float fl4 __attribute__((ext_vector_type(4)));
typedef __bf16 bf16x8 __attribute__((ext_vector_type(8)));
typedef unsigned short us8 __attribute__((ext_vector_type(8)));
typedef unsigned short us4 __attribute__((ext_vector_type(4)));

// ---------- bf16 helpers ----------
__device__ __forceinline__ unsigned short f32_bf16_rne(float f) {
  uint32_t u = __builtin_bit_cast(uint32_t, f);
  return (unsigned short)((u + 0x7FFFu + ((u >> 16) & 1u)) >> 16);
}
__device__ __forceinline__ float bf16_f32(unsigned short h) {
  uint32_t u = ((uint32_t)h) << 16;
  return __builtin_bit_cast(float, u);
}

// bank-spread swizzle for 32-row b128 fragment reads:
// phys_chunk = logical_chunk ^ SW(row);  SW covers row bits 1..4 so rows
// {r, r+2, ..} AND {r, r+8, r+16, r+24} land on distinct bank groups.
__device__ __forceinline__ int swz_row(int r) {
  return ((r >> 1) & 3) ^ ((r >> 3) & 3);
}

// ---------- global->LDS direct ----------
__device__ __forceinline__ void gload16(const void* g, void* l) {
  __builtin_amdgcn_global_load_lds(
      reinterpret_cast<const __attribute__((address_space(1))) uint32_t*>(
          reinterpret_cast<uintptr_t>(g)),
      reinterpret_cast<__attribute__((address_space(3))) uint32_t*>(
          reinterpret_cast<uintptr_t>(l)),
      16, 0, 0);
}

__device__ __forceinline__ bf16x8 ldfrag(const unsigned short* p) {
  us8 u = *reinterpret_cast<const us8*>(p);
  return __builtin_bit_cast(bf16x8, u);
}

// ---------- split f32 -> (hi, lo) bf16 ----------
__global__ __launch_bounds__(256) void k_split(const float* __restrict__ in, int n4,
                                               unsigned short* __restrict__ hi,
                                               unsigned short* __restrict__ lo) {
  int stride = gridDim.x * blockDim.x;
  for (int i = blockIdx.x * blockDim.x + threadIdx.x; i < n4; i += stride) {
    fl4 v = ((const fl4*)in)[i];
    us4 h, l;
#pragma unroll
    for (int j = 0; j < 4; ++j) {
      unsigned short hb = f32_bf16_rne(v[j]);
      float rem = v[j] - bf16_f32(hb);
      h[j] = hb;
      l[j] = f32_bf16_rne(rem);
    }
    ((us4*)hi)[i] = h;
    ((us4*)lo)[i] = l;
  }
}

__global__ __launch_bounds__(256) void k_split_hi(const float* __restrict__ in, int n4,
                                                  unsigned short* __restrict__ hi) {
  int stride = gridDim.x * blockDim.x;
  for (int i = blockIdx.x * blockDim.x + threadIdx.x; i < n4; i += stride) {
    fl4 v = ((const fl4*)in)[i];
    us4 h;
#pragma unroll
    for (int j = 0; j < 4; ++j) h[j] = f32_bf16_rne(v[j]);
    ((us4*)hi)[i] = h;
  }
}

// ---------- transpose-split: out_t[d][e] = split(in[e][d]), 64x64 tiles ----------
__global__ __launch_bounds__(256) void k_split_T(const float* __restrict__ in,
                                                 unsigned short* __restrict__ th,
                                                 unsigned short* __restrict__ tl) {
  __shared__ float tile[64][69];
  int be = blockIdx.x >> 4, bd = blockIdx.x & 15;
  int e0 = be * 64, d0 = bd * 64;
  int r = threadIdx.x >> 4;
  int c = (threadIdx.x & 15) * 4;
#pragma unroll
  for (int it = 0; it < 4; ++it) {
    int rr = r + it * 16;
    fl4 v = *(const fl4*)(in + (size_t)(e0 + rr) * D_DIM + d0 + c);
#pragma unroll
    for (int j = 0; j < 4; ++j) tile[rr][c + j] = v[j];
  }
  __syncthreads();
#pragma unroll
  for (int it = 0; it < 4; ++it) {
    int dr = r + it * 16;
    us4 h, l;
#pragma unroll
    for (int j = 0; j < 4; ++j) {
      float f = tile[c + j][dr];
      h[j] = f32_bf16_rne(f);
      l[j] = f32_bf16_rne(f - bf16_f32(h[j]));
    }
    *(us4*)(th + (size_t)(d0 + dr) * D_DIM + e0 + c) = h;
    *(us4*)(tl + (size_t)(d0 + dr) * D_DIM + e0 + c) = l;
  }
}

// ---------- u[t] = GAMMA * rowsum(W_ih[t,:]) + b_ih[t], one wave per row ----------
__global__ __launch_bounds__(256) void k_u(const float* __restrict__ Wih,
                                           const float* __restrict__ bih,
                                           float* __restrict__ u) {
  int wave = threadIdx.x >> 6, lane = threadIdx.x & 63;
  int t = blockIdx.x * 4 + wave;
  const fl4* row = (const fl4*)(Wih + (size_t)t * T_DIM);
  float s = 0.f;
#pragma unroll
  for (int i = 0; i < 8; ++i) {
    fl4 v = row[lane + i * 64];
    s += v[0] + v[1] + v[2] + v[3];
  }
#pragma unroll
  for (int m = 32; m >= 1; m >>= 1) s += __shfl_xor(s, m, 64);
  if (lane == 0) u[t] = GAMMA_C * s + bih[t];
}

// ---------- h_out[t] = tanh(u[t] + dot(Whh_bf16[t,:], h_prev) + bias_row[t]) ----------
__global__ __launch_bounds__(256) void k_step_bf(const unsigned short* __restrict__ Whh_b,
                                                 const float* __restrict__ hprev,
                                                 const float* __restrict__ u,
                                                 const float* __restrict__ biasrow,
                                                 float* __restrict__ hout) {
  int wave = threadIdx.x >> 6, lane = threadIdx.x & 63;
  int t = blockIdx.x * 4 + wave;
  const unsigned short* row = Whh_b + (size_t)t * T_DIM;
  float s = 0.f;
#pragma unroll
  for (int i = 0; i < 4; ++i) {
    us8 w = *(const us8*)(row + i * 512 + lane * 8);
    fl4 h0 = *(const fl4*)(hprev + i * 512 + lane * 8);
    fl4 h1 = *(const fl4*)(hprev + i * 512 + lane * 8 + 4);
    s += bf16_f32(w[0]) * h0[0] + bf16_f32(w[1]) * h0[1] +
         bf16_f32(w[2]) * h0[2] + bf16_f32(w[3]) * h0[3] +
         bf16_f32(w[4]) * h1[0] + bf16_f32(w[5]) * h1[1] +
         bf16_f32(w[6]) * h1[2] + bf16_f32(w[7]) * h1[3];
  }
#pragma unroll
  for (int m = 32; m >= 1; m >>= 1) s += __shfl_xor(s, m, 64);
  if (lane == 0) hout[t] = tanhf(u[t] + s + biasrow[t]);
}

// XCD-chunked block mapping for 1024-block GEMM grids (128 mb x 8 nb)
__device__ __forceinline__ void map_blk(int bid, int& mb, int& nb) {
  int sw = (bid & 7) * 128 + (bid >> 3);
  mb = sw >> 3;
  nb = sw & 7;
}

// =====================================================================
// Ht[d'][d] = sum_e Wv[e,d'] * Wk[e,d], 3-term split, epilogue re-split.
// 64x64 tiles, 256 blocks, 4 waves (2x2), per-wave one 32x32, MFMA 32x32x16.
// =====================================================================
__global__ __launch_bounds__(256) void k_ht(
    const unsigned short* __restrict__ ah, const unsigned short* __restrict__ al,
    const unsigned short* __restrict__ bh, const unsigned short* __restrict__ bl,
    unsigned short* __restrict__ outh, unsigned short* __restrict__ outl) {
  __shared__ unsigned short sAh[2][64 * 32], sAl[2][64 * 32];
  __shared__ unsigned short sBh[2][64 * 32], sBl[2][64 * 32];
  const int tid = threadIdx.x;
  const int wave = tid >> 6, lane = tid & 63;
  const int wm = wave >> 1, wn = wave & 1;
  const int m0 = (blockIdx.x >> 4) * 64, n0 = (blockIdx.x & 15) * 64;
  const int hi32 = lane >> 5;

  const int srow = tid >> 2;
  const int csrc = (tid & 3) ^ swz_row(srow);
  const size_t ga = (size_t)(m0 + srow) * D_DIM + csrc * 8;
  const size_t gb = (size_t)(n0 + srow) * D_DIM + csrc * 8;
  const int ldst = tid * 8;

  f32x16 acc = {};
  const int l31 = lane & 31;
  const int sw = swz_row(l31);
  const int ar = wm * 32 + l31;
  const int br = wn * 32 + l31;
  int aoff[2], boff[2];
#pragma unroll
  for (int kh = 0; kh < 2; ++kh) {
    aoff[kh] = ar * 32 + (((kh * 2 + hi32) ^ sw) * 8);
    boff[kh] = br * 32 + (((kh * 2 + hi32) ^ sw) * 8);
  }

#define HT_STAGE(t, buf)                         \
  do {                                           \
    const size_t ko = (size_t)(t) * 32;          \
    gload16(ah + ga + ko, &sAh[buf][ldst]);      \
    gload16(al + ga + ko, &sAl[buf][ldst]);      \
    gload16(bh + gb + ko, &sBh[buf][ldst]);      \
    gload16(bl + gb + ko, &sBl[buf][ldst]);      \
  } while (0)

  HT_STAGE(0, 0);
  __syncthreads();
  for (int kt = 0; kt < 32; ++kt) {
    const int cur = kt & 1;
    if (kt < 31) HT_STAGE(kt + 1, cur ^ 1);
#pragma unroll
    for (int kh = 0; kh < 2; ++kh) {
      bf16x8 fah = ldfrag(&sAh[cur][aoff[kh]]);
      bf16x8 fal = ldfrag(&sAl[cur][aoff[kh]]);
      bf16x8 fbh = ldfrag(&sBh[cur][boff[kh]]);
      bf16x8 fbl = ldfrag(&sBl[cur][boff[kh]]);
      acc = __builtin_amdgcn_mfma_f32_32x32x16_bf16(fah, fbh, acc, 0, 0, 0);
      acc = __builtin_amdgcn_mfma_f32_32x32x16_bf16(fah, fbl, acc, 0, 0, 0);
      acc = __builtin_amdgcn_mfma_f32_32x32x16_bf16(fal, fbh, acc, 0, 0, 0);
    }
    __syncthreads();
  }
#pragma unroll
  for (int r = 0; r < 16; ++r) {
    int row = m0 + wm * 32 + (r & 3) + 8 * (r >> 2) + 4 * hi32;
    int col = n0 + wn * 32 + l31;
    float f = acc[r];
    unsigned short hb = f32_bf16_rne(f);
    unsigned short lb = f32_bf16_rne(f - bf16_f32(hb));
    size_t ad = (size_t)row * D_DIM + col;
    outh[ad] = hb;
    outl[ad] = lb;
  }
#undef HT_STAGE
}

// =====================================================================
// Y = x.Ht^T fused bias: bias[t] += sum_{d' in block} x[t,d'] * Y[t,d'].
// 3-term split. BM=BN=128, BK=32, 4 waves (2x2), per-wave 64x64,
// MFMA 32x32x16, acc[2][2]. LDS 64KB -> 2 blocks/CU.
// reads:MFMA per wave per kt = 16:24 -> LDS pipe ~= MFMA pipe (balanced).
// =====================================================================
__global__ __launch_bounds__(256, 2) void k_y_bias(
    const unsigned short* __restrict__ xh, const unsigned short* __restrict__ xl,
    const unsigned short* __restrict__ bh, const unsigned short* __restrict__ bl,
    const float* __restrict__ xf, float* __restrict__ bias) {
  __shared__ unsigned short sAh[2][128 * 32], sAl[2][128 * 32];
  __shared__ unsigned short sBh[2][128 * 32], sBl[2][128 * 32];
  const int tid = threadIdx.x;
  const int wave = tid >> 6, lane = tid & 63;
  const int wm = wave >> 1, wn = wave & 1;
  int mb, nb;
  map_blk(blockIdx.x, mb, nb);
  const int m0 = mb * 128, n0 = nb * 128;
  const int hi32 = lane >> 5;

  // staging: 256 threads x 2 passes cover 128 rows x 32 cols per array
  const int srow0 = tid >> 2, srow1 = srow0 + 64;
  const int csrc0 = (tid & 3) ^ swz_row(srow0);
  const int csrc1 = (tid & 3) ^ swz_row(srow1);
  const size_t gaA0 = (size_t)(m0 + srow0) * D_DIM + csrc0 * 8;
  const size_t gaA1 = (size_t)(m0 + srow1) * D_DIM + csrc1 * 8;
  const size_t gaB0 = (size_t)(n0 + srow0) * D_DIM + csrc0 * 8;
  const size_t gaB1 = (size_t)(n0 + srow1) * D_DIM + csrc1 * 8;
  const int ldst0 = tid * 8, ldst1 = (tid + 256) * 8;

  f32x16 acc[2][2] = {};
  const int l31 = lane & 31;
  const int sw = swz_row(l31);
  int aoff[2][2], boff[2][2];
#pragma unroll
  for (int mi = 0; mi < 2; ++mi) {
    int r = wm * 64 + mi * 32 + l31;
#pragma unroll
    for (int kh = 0; kh < 2; ++kh)
      aoff[mi][kh] = r * 32 + (((kh * 2 + hi32) ^ sw) * 8);
  }
#pragma unroll
  for (int ni = 0; ni < 2; ++ni) {
    int r = wn * 64 + ni * 32 + l31;
#pragma unroll
    for (int kh = 0; kh < 2; ++kh)
      boff[ni][kh] = r * 32 + (((kh * 2 + hi32) ^ sw) * 8);
  }

#define Y_STAGE(t, buf)                           \
  do {                                            \
    const size_t ko = (size_t)(t) * 32;           \
    gload16(xh + gaA0 + ko, &sAh[buf][ldst0]);    \
    gload16(xh + gaA1 + ko, &sAh[buf][ldst1]);    \
    gload16(xl + gaA0 + ko, &sAl[buf][ldst0]);    \
    gload16(xl + gaA1 + ko, &sAl[buf][ldst1]);    \
    gload16(bh + gaB0 + ko, &sBh[buf][ldst0]);    \
    gload16(bh + gaB1 + ko, &sBh[buf][ldst1]);    \
    gload16(bl + gaB0 + ko, &sBl[buf][ldst0]);    \
    gload16(bl + gaB1 + ko, &sBl[buf][ldst1]);    \
  } while (0)

  Y_STAGE(0, 0);
  __syncthreads();
  for (int kt = 0; kt < 32; ++kt) {
    const int cur = kt & 1;
    if (kt < 31) Y_STAGE(kt + 1, cur ^ 1);
#pragma unroll
    for (int kh = 0; kh < 2; ++kh) {
      bf16x8 fah[2], fal[2], fbh_[2], fbl_[2];
#pragma unroll
      for (int mi = 0; mi < 2; ++mi) {
        fah[mi] = ldfrag(&sAh[cur][aoff[mi][kh]]);
        fal[mi] = ldfrag(&sAl[cur][aoff[mi][kh]]);
      }
#pragma unroll
      for (int ni = 0; ni < 2; ++ni) {
        fbh_[ni] = ldfrag(&sBh[cur][boff[ni][kh]]);
        fbl_[ni] = ldfrag(&sBl[cur][boff[ni][kh]]);
      }
      __builtin_amdgcn_s_setprio(1);
#pragma unroll
      for (int mi = 0; mi < 2; ++mi)
#pragma unroll
        for (int ni = 0; ni < 2; ++ni) {
          acc[mi][ni] = __builtin_amdgcn_mfma_f32_32x32x16_bf16(fah[mi], fbh_[ni], acc[mi][ni], 0, 0, 0);
          acc[mi][ni] = __builtin_amdgcn_mfma_f32_32x32x16_bf16(fah[mi], fbl_[ni], acc[mi][ni], 0, 0, 0);
          acc[mi][ni] = __builtin_amdgcn_mfma_f32_32x32x16_bf16(fal[mi], fbh_[ni], acc[mi][ni], 0, 0, 0);
        }
      __builtin_amdgcn_s_setprio(0);
    }
    __syncthreads();
  }

  // bias fold: p = sum_ni x[row,col_ni] * Y_acc[ni], half-wave reduce, atomic.
#pragma unroll
  for (int mi = 0; mi < 2; ++mi)
#pragma unroll
    for (int r = 0; r < 16; ++r) {
      int row = m0 + wm * 64 + mi * 32 + (r & 3) + 8 * (r >> 2) + 4 * hi32;
      const float* xr = xf + (size_t)row * D_DIM + n0 + wn * 64 + l31;
      float p = xr[0] * acc[mi][0][r] + xr[32] * acc[mi][1][r];
      p += __shfl_xor(p, 1, 64);
      p += __shfl_xor(p, 2, 64);
      p += __shfl_xor(p, 4, 64);
      p += __shfl_xor(p, 8, 64);
      p += __shfl_xor(p, 16, 64);
      if (l31 == 0) atomicAdd(&bias[row], p);
    }
#undef Y_STAGE
}

// =====================================================================
// Q plain-bf16 GEMM with epilogue out[t,e] = S[t] * Q[t,e].
// BM=BN=128, BK=32, 4 waves (2x2), per-wave 64x64, MFMA 32x32x16.
// LDS 32KB -> 4 blocks/CU.
// =====================================================================
__global__ __launch_bounds__(256, 4) void k_q_out(
    const unsigned short* __restrict__ xh,
    const unsigned short* __restrict__ qh_,
    const float* __restrict__ S, float* __restrict__ out) {
  __shared__ unsigned short sA[2][128 * 32];
  __shared__ unsigned short sB[2][128 * 32];
  const int tid = threadIdx.x;
  const int wave = tid >> 6, lane = tid & 63;
  const int wm = wave >> 1, wn = wave & 1;
  int mb, nb;
  map_blk(blockIdx.x, mb, nb);
  const int m0 = mb * 128, n0 = nb * 128;
  const int hi32 = lane >> 5;

  const int srow0 = tid >> 2, srow1 = srow0 + 64;
  const int csrc0 = (tid & 3) ^ swz_row(srow0);
  const int csrc1 = (tid & 3) ^ swz_row(srow1);
  const size_t gaA0 = (size_t)(m0 + srow0) * D_DIM + csrc0 * 8;
  const size_t gaA1 = (size_t)(m0 + srow1) * D_DIM + csrc1 * 8;
  const size_t gaB0 = (size_t)(n0 + srow0) * D_DIM + csrc0 * 8;
  const size_t gaB1 = (size_t)(n0 + srow1) * D_DIM + csrc1 * 8;
  const int ldst0 = tid * 8, ldst1 = (tid + 256) * 8;

  f32x16 acc[2][2] = {};
  const int l31 = lane & 31;
  const int sw = swz_row(l31);
  int aoff[2][2], boff[2][2];
#pragma unroll
  for (int mi = 0; mi < 2; ++mi) {
    int r = wm * 64 + mi * 32 + l31;
#pragma unroll
    for (int kh = 0; kh < 2; ++kh)
      aoff[mi][kh] = r * 32 + (((kh * 2 + hi32) ^ sw) * 8);
  }
#pragma unroll
  for (int ni = 0; ni < 2; ++ni) {
    int r = wn * 64 + ni * 32 + l31;
#pragma unroll
    for (int kh = 0; kh < 2; ++kh)
      boff[ni][kh] = r * 32 + (((kh * 2 + hi32) ^ sw) * 8);
  }

#define Q_STAGE(t, buf)                           \
  do {                                            \
    const size_t ko = (size_t)(t) * 32;           \
    gload16(xh + gaA0 + ko, &sA[buf][ldst0]);     \
    gload16(xh + gaA1 + ko, &sA[buf][ldst1]);     \
    gload16(qh_ + gaB0 + ko, &sB[buf][ldst0]);    \
    gload16(qh_ + gaB1 + ko, &sB[buf][ldst1]);    \
  } while (0)

  Q_STAGE(0, 0);
  __syncthreads();
  for (int kt = 0; kt < 32; ++kt) {
    const int cur = kt & 1;
    if (kt < 31) Q_STAGE(kt + 1, cur ^ 1);
#pragma unroll
    for (int kh = 0; kh < 2; ++kh) {
      bf16x8 fa[2], fb[2];
#pragma unroll
      for (int mi = 0; mi < 2; ++mi) fa[mi] = ldfrag(&sA[cur][aoff[mi][kh]]);
#pragma unroll
      for (int ni = 0; ni < 2; ++ni) fb[ni] = ldfrag(&sB[cur][boff[ni][kh]]);
      __builtin_amdgcn_s_setprio(1);
#pragma unroll
      for (int mi = 0; mi < 2; ++mi)
#pragma unroll
        for (int ni = 0; ni < 2; ++ni)
          acc[mi][ni] = __builtin_amdgcn_mfma_f32_32x32x16_bf16(fa[mi], fb[ni], acc[mi][ni], 0, 0, 0);
      __builtin_amdgcn_s_setprio(0);
    }
    __syncthreads();
  }

#pragma unroll
  for (int mi = 0; mi < 2; ++mi)
#pragma unroll
    for (int r = 0; r < 16; ++r) {
      int row = m0 + wm * 64 + mi * 32 + (r & 3) + 8 * (r >> 2) + 4 * hi32;
      float sc = S[row];
      float* orow = out + (size_t)row * D_DIM + n0 + wn * 64 + l31;
      orow[0] = sc * acc[mi][0][r];
      orow[32] = sc * acc[mi][1][r];
    }
#undef Q_STAGE
}

// =====================================================================
extern "C" void kernel_launch(void* const* d_in, const int* in_sizes, int n_in,
                              void* d_out, int out_size, void* d_ws, size_t ws_size,
                              hipStream_t stream) {
  const float* x   = (const float*)d_in[0];
  const float* Wq  = (const float*)d_in[1];
  const float* Wk  = (const float*)d_in[2];
  const float* Wv  = (const float*)d_in[3];
  const float* Wih = (const float*)d_in[4];
  const float* Whh = (const float*)d_in[5];
  const float* bih = (const float*)d_in[6];
  float* out = (float*)d_out;

  char* ws = (char*)d_ws;
  size_t off = 0;
  auto alloc = [&](size_t bytes) -> char* {
    char* p = ws + off;
    off += (bytes + 255) & ~(size_t)255;
    return p;
  };
  unsigned short* xh   = (unsigned short*)alloc((size_t)M_TOK * D_DIM * 2);
  unsigned short* xl   = (unsigned short*)alloc((size_t)M_TOK * D_DIM * 2);
  unsigned short* wqh  = (unsigned short*)alloc((size_t)D_DIM * D_DIM * 2);
  unsigned short* wkth = (unsigned short*)alloc((size_t)D_DIM * D_DIM * 2);
  unsigned short* wktl = (unsigned short*)alloc((size_t)D_DIM * D_DIM * 2);
  unsigned short* wvth = (unsigned short*)alloc((size_t)D_DIM * D_DIM * 2);
  unsigned short* wvtl = (unsigned short*)alloc((size_t)D_DIM * D_DIM * 2);
  unsigned short* hth  = (unsigned short*)alloc((size_t)D_DIM * D_DIM * 2);
  unsigned short* htl  = (unsigned short*)alloc((size_t)D_DIM * D_DIM * 2);
  float* bias = (float*)alloc((size_t)M_TOK * 4);
  float* Sbuf = (float*)alloc((size_t)M_TOK * 4);
  float* ubuf = (float*)alloc((size_t)T_DIM * 4);
  float* zbuf = (float*)alloc((size_t)T_DIM * 4);
  // Whh bf16 (8 MB) aliases wkth..wvtl (4 x 2 MB, dead after k_ht).
  unsigned short* whhb = wkth;
  (void)ws_size; (void)in_sizes; (void)n_in; (void)out_size;

  // 1. splits
  k_split<<<2048, 256, 0, stream>>>(x, M_TOK * D_DIM / 4, xh, xl);
  k_split_hi<<<512, 256, 0, stream>>>(Wq, D_DIM * D_DIM / 4, wqh);
  k_split_T<<<256, 256, 0, stream>>>(Wk, wkth, wktl);
  k_split_T<<<256, 256, 0, stream>>>(Wv, wvth, wvtl);

  // 2. zero bias accumulator and h0
  hipMemsetAsync(bias, 0, (size_t)M_TOK * 4, stream);
  hipMemsetAsync(zbuf, 0, (size_t)T_DIM * 4, stream);

  // 3. u vector
  k_u<<<T_DIM / 4, 256, 0, stream>>>(Wih, bih, ubuf);

  // 4. Ht[d'][d] = sum_e Wv[e,d'] Wk[e,d]  (A=wvt, B=wkt)
  k_ht<<<256, 256, 0, stream>>>(wvth, wvtl, wkth, wktl, hth, htl);

  // 5. Whh -> bf16 (after k_ht: aliases the transposed weight splits)
  k_split_hi<<<1024, 256, 0, stream>>>(Whh, T_DIM * T_DIM / 4, whhb);

  // 6. Y = x.Ht fused into bias = rowdot(x, Y)
  k_y_bias<<<1024, 256, 0, stream>>>(xh, xl, hth, htl, x, bias);

  // 7. 8-step tanh recurrence over batch rows (wave per row)
  for (int b = 0; b < B_DIM; ++b) {
    const float* hp = (b == 0) ? zbuf : (Sbuf + (size_t)(b - 1) * T_DIM);
    k_step_bf<<<T_DIM / 4, 256, 0, stream>>>(whhb, hp, ubuf, bias + (size_t)b * T_DIM,
                                             Sbuf + (size_t)b * T_DIM);
  }

  // 8. Q GEMM + scale-by-S epilogue
  k_q_out<<<1024, 256, 0, stream>>>(xh, wqh, Sbuf, out);
}

// Round 5
// 261.691 us; speedup vs baseline: 1.3035x; 1.0212x over previous
//
#include <hip/hip_runtime.h>
#include <stdint.h>

#define T_DIM 2048
#define D_DIM 1024
#define B_DIM 8
#define M_TOK (B_DIM * T_DIM)   // 16384 tokens
#define GAMMA_C 0.96875f

typedef float f32x4 __attribute__((ext_vector_type(4)));
typedef float f32x16 __attribute__((ext_vector_type(16)));
typedef float fl4 __attribute__((ext_vector_type(4)));
typedef __bf16 bf16x8 __attribute__((ext_vector_type(8)));
typedef unsigned short us8 __attribute__((ext_vector_type(8)));
typedef unsigned short us4 __attribute__((ext_vector_type(4)));

// ---------- bf16 helpers ----------
__device__ __forceinline__ unsigned short f32_bf16_rne(float f) {
  uint32_t u = __builtin_bit_cast(uint32_t, f);
  return (unsigned short)((u + 0x7FFFu + ((u >> 16) & 1u)) >> 16);
}
__device__ __forceinline__ float bf16_f32(unsigned short h) {
  uint32_t u = ((uint32_t)h) << 16;
  return __builtin_bit_cast(float, u);
}

// chunk swizzle: spreads 32-row b128 column-slice reads across bank groups
__device__ __forceinline__ int swz_row(int r) {
  return ((r >> 1) & 3) ^ ((r >> 3) & 3);
}

// ---------- global->LDS direct ----------
__device__ __forceinline__ void gload16(const void* g, void* l) {
  __builtin_amdgcn_global_load_lds(
      reinterpret_cast<const __attribute__((address_space(1))) uint32_t*>(
          reinterpret_cast<uintptr_t>(g)),
      reinterpret_cast<__attribute__((address_space(3))) uint32_t*>(
          reinterpret_cast<uintptr_t>(l)),
      16, 0, 0);
}

__device__ __forceinline__ bf16x8 ldfrag(const unsigned short* p) {
  us8 u = *reinterpret_cast<const us8*>(p);
  return __builtin_bit_cast(bf16x8, u);
}

// ---------- split f32 -> (hi, lo) bf16, 16B stores ----------
__global__ __launch_bounds__(256) void k_split(const float* __restrict__ in, int n8,
                                               unsigned short* __restrict__ hi,
                                               unsigned short* __restrict__ lo) {
  int stride = gridDim.x * blockDim.x;
  for (int i = blockIdx.x * blockDim.x + threadIdx.x; i < n8; i += stride) {
    fl4 v0 = ((const fl4*)in)[i * 2];
    fl4 v1 = ((const fl4*)in)[i * 2 + 1];
    us8 h, l;
#pragma unroll
    for (int j = 0; j < 4; ++j) {
      unsigned short hb = f32_bf16_rne(v0[j]);
      h[j] = hb;
      l[j] = f32_bf16_rne(v0[j] - bf16_f32(hb));
      unsigned short hb1 = f32_bf16_rne(v1[j]);
      h[j + 4] = hb1;
      l[j + 4] = f32_bf16_rne(v1[j] - bf16_f32(hb1));
    }
    ((us8*)hi)[i] = h;
    ((us8*)lo)[i] = l;
  }
}

__global__ __launch_bounds__(256) void k_split_hi(const float* __restrict__ in, int n8,
                                                  unsigned short* __restrict__ hi) {
  int stride = gridDim.x * blockDim.x;
  for (int i = blockIdx.x * blockDim.x + threadIdx.x; i < n8; i += stride) {
    fl4 v0 = ((const fl4*)in)[i * 2];
    fl4 v1 = ((const fl4*)in)[i * 2 + 1];
    us8 h;
#pragma unroll
    for (int j = 0; j < 4; ++j) {
      h[j] = f32_bf16_rne(v0[j]);
      h[j + 4] = f32_bf16_rne(v1[j]);
    }
    ((us8*)hi)[i] = h;
  }
}

// ---------- transpose-split: out_t[d][e] = split(in[e][d]), 64x64 tiles ----------
__global__ __launch_bounds__(256) void k_split_T(const float* __restrict__ in,
                                                 unsigned short* __restrict__ th,
                                                 unsigned short* __restrict__ tl) {
  __shared__ float tile[64][69];
  int be = blockIdx.x >> 4, bd = blockIdx.x & 15;
  int e0 = be * 64, d0 = bd * 64;
  int r = threadIdx.x >> 4;
  int c = (threadIdx.x & 15) * 4;
#pragma unroll
  for (int it = 0; it < 4; ++it) {
    int rr = r + it * 16;
    fl4 v = *(const fl4*)(in + (size_t)(e0 + rr) * D_DIM + d0 + c);
#pragma unroll
    for (int j = 0; j < 4; ++j) tile[rr][c + j] = v[j];
  }
  __syncthreads();
#pragma unroll
  for (int it = 0; it < 4; ++it) {
    int dr = r + it * 16;
    us4 h, l;
#pragma unroll
    for (int j = 0; j < 4; ++j) {
      float f = tile[c + j][dr];
      h[j] = f32_bf16_rne(f);
      l[j] = f32_bf16_rne(f - bf16_f32(h[j]));
    }
    *(us4*)(th + (size_t)(d0 + dr) * D_DIM + e0 + c) = h;
    *(us4*)(tl + (size_t)(d0 + dr) * D_DIM + e0 + c) = l;
  }
}

// ---------- u[t] = GAMMA * rowsum(W_ih[t,:]) + b_ih[t], one wave per row ----------
__global__ __launch_bounds__(256) void k_u(const float* __restrict__ Wih,
                                           const float* __restrict__ bih,
                                           float* __restrict__ u) {
  int wave = threadIdx.x >> 6, lane = threadIdx.x & 63;
  int t = blockIdx.x * 4 + wave;
  const fl4* row = (const fl4*)(Wih + (size_t)t * T_DIM);
  float s = 0.f;
#pragma unroll
  for (int i = 0; i < 8; ++i) {
    fl4 v = row[lane + i * 64];
    s += v[0] + v[1] + v[2] + v[3];
  }
#pragma unroll
  for (int m = 32; m >= 1; m >>= 1) s += __shfl_xor(s, m, 64);
  if (lane == 0) u[t] = GAMMA_C * s + bih[t];
}

// ---------- h_out[t] = tanh(u[t] + dot(Whh_bf16[t,:], h_prev) + bias_row[t]) ----------
__global__ __launch_bounds__(256) void k_step_bf(const unsigned short* __restrict__ Whh_b,
                                                 const float* __restrict__ hprev,
                                                 const float* __restrict__ u,
                                                 const float* __restrict__ biasrow,
                                                 float* __restrict__ hout) {
  int wave = threadIdx.x >> 6, lane = threadIdx.x & 63;
  int t = blockIdx.x * 4 + wave;
  const unsigned short* row = Whh_b + (size_t)t * T_DIM;
  float s = 0.f;
#pragma unroll
  for (int i = 0; i < 4; ++i) {
    us8 w = *(const us8*)(row + i * 512 + lane * 8);
    fl4 h0 = *(const fl4*)(hprev + i * 512 + lane * 8);
    fl4 h1 = *(const fl4*)(hprev + i * 512 + lane * 8 + 4);
    s += bf16_f32(w[0]) * h0[0] + bf16_f32(w[1]) * h0[1] +
         bf16_f32(w[2]) * h0[2] + bf16_f32(w[3]) * h0[3] +
         bf16_f32(w[4]) * h1[0] + bf16_f32(w[5]) * h1[1] +
         bf16_f32(w[6]) * h1[2] + bf16_f32(w[7]) * h1[3];
  }
#pragma unroll
  for (int m = 32; m >= 1; m >>= 1) s += __shfl_xor(s, m, 64);
  if (lane == 0) hout[t] = tanhf(u[t] + s + biasrow[t]);
}

// XCD-chunked block mapping for 1024-block GEMM grids (128 mb x 8 nb)
__device__ __forceinline__ void map_blk(int bid, int& mb, int& nb) {
  int sw = (bid & 7) * 128 + (bid >> 3);
  mb = sw >> 3;
  nb = sw & 7;
}

// =====================================================================
// H[d'][d] = sum_e Wv[e,d'] * Wk[e,d], 3-term split, fp32 output.
// 64x64 tiles, 256 blocks, 4 waves (2x2), per-wave one 32x32, MFMA 32x32x16.
// =====================================================================
__global__ __launch_bounds__(256) void k_ht(
    const unsigned short* __restrict__ ah, const unsigned short* __restrict__ al,
    const unsigned short* __restrict__ bh, const unsigned short* __restrict__ bl,
    float* __restrict__ Hf) {
  __shared__ unsigned short sAh[2][64 * 32], sAl[2][64 * 32];
  __shared__ unsigned short sBh[2][64 * 32], sBl[2][64 * 32];
  const int tid = threadIdx.x;
  const int wave = tid >> 6, lane = tid & 63;
  const int wm = wave >> 1, wn = wave & 1;
  const int m0 = (blockIdx.x >> 4) * 64, n0 = (blockIdx.x & 15) * 64;
  const int hi32 = lane >> 5;

  const int srow = tid >> 2;
  const int csrc = (tid & 3) ^ swz_row(srow);
  const size_t ga = (size_t)(m0 + srow) * D_DIM + csrc * 8;
  const size_t gb = (size_t)(n0 + srow) * D_DIM + csrc * 8;
  const int ldst = tid * 8;

  f32x16 acc = {};
  const int l31 = lane & 31;
  const int sw = swz_row(l31);
  const int ar = wm * 32 + l31;
  const int br = wn * 32 + l31;
  int aoff[2], boff[2];
#pragma unroll
  for (int kh = 0; kh < 2; ++kh) {
    aoff[kh] = ar * 32 + (((kh * 2 + hi32) ^ sw) * 8);
    boff[kh] = br * 32 + (((kh * 2 + hi32) ^ sw) * 8);
  }

#define HT_STAGE(t, buf)                         \
  do {                                           \
    const size_t ko = (size_t)(t) * 32;          \
    gload16(ah + ga + ko, &sAh[buf][ldst]);      \
    gload16(al + ga + ko, &sAl[buf][ldst]);      \
    gload16(bh + gb + ko, &sBh[buf][ldst]);      \
    gload16(bl + gb + ko, &sBl[buf][ldst]);      \
  } while (0)

  HT_STAGE(0, 0);
  __syncthreads();
  for (int kt = 0; kt < 32; ++kt) {
    const int cur = kt & 1;
    if (kt < 31) HT_STAGE(kt + 1, cur ^ 1);
#pragma unroll
    for (int kh = 0; kh < 2; ++kh) {
      bf16x8 fah = ldfrag(&sAh[cur][aoff[kh]]);
      bf16x8 fal = ldfrag(&sAl[cur][aoff[kh]]);
      bf16x8 fbh = ldfrag(&sBh[cur][boff[kh]]);
      bf16x8 fbl = ldfrag(&sBl[cur][boff[kh]]);
      acc = __builtin_amdgcn_mfma_f32_32x32x16_bf16(fah, fbh, acc, 0, 0, 0);
      acc = __builtin_amdgcn_mfma_f32_32x32x16_bf16(fah, fbl, acc, 0, 0, 0);
      acc = __builtin_amdgcn_mfma_f32_32x32x16_bf16(fal, fbh, acc, 0, 0, 0);
    }
    __syncthreads();
  }
#pragma unroll
  for (int r = 0; r < 16; ++r) {
    int row = m0 + wm * 32 + (r & 3) + 8 * (r >> 2) + 4 * hi32;
    int col = n0 + wn * 32 + l31;
    Hf[(size_t)row * D_DIM + col] = acc[r];
  }
#undef HT_STAGE
}

// =====================================================================
// M'[d'][d] = H[d',d]+H[d,d'] (d>d'); H[d,d] (d==d'); 0 (d<d').
// xT M' x == xT H x exactly, and M' is upper-triangular -> the Y-GEMM
// only needs K-range d >= n0 per N-block (56% of the K-work).
// 64x64 output tiles; transpose tile staged via LDS. hi/lo split output.
// =====================================================================
__global__ __launch_bounds__(256) void k_nprime(const float* __restrict__ Hf,
                                                unsigned short* __restrict__ mh,
                                                unsigned short* __restrict__ ml) {
  __shared__ float t2[64][65];
  const int ti = blockIdx.x >> 4;   // d' tile
  const int tj = blockIdx.x & 15;   // d  tile
  const int r0 = ti * 64, c0 = tj * 64;
  const int a = threadIdx.x >> 2;          // 0..63
  const int b4 = (threadIdx.x & 3) * 16;   // col group of 16
  if (tj < ti) {  // strict lower tile: zeros
#pragma unroll
    for (int j = 0; j < 16; ++j) {
      size_t ad = (size_t)(r0 + a) * D_DIM + c0 + b4 + j;
      mh[ad] = 0;
      ml[ad] = 0;
    }
    return;
  }
  // stage Hf rows (c0..c0+63) x cols (r0..r0+63): t2[r][c] = H[c0+r][r0+c]
#pragma unroll
  for (int j = 0; j < 16; j += 4) {
    fl4 v = *(const fl4*)(Hf + (size_t)(c0 + a) * D_DIM + r0 + b4 + j);
#pragma unroll
    for (int q = 0; q < 4; ++q) t2[a][b4 + j + q] = v[q];
  }
  __syncthreads();
#pragma unroll
  for (int j = 0; j < 16; ++j) {
    int dp = r0 + a;        // d'
    int dd = c0 + b4 + j;   // d
    float v = 0.f;
    if (dd > dp)       v = Hf[(size_t)dp * D_DIM + dd] + t2[b4 + j][a];
    else if (dd == dp) v = Hf[(size_t)dp * D_DIM + dd];
    unsigned short hb = f32_bf16_rne(v);
    unsigned short lb = f32_bf16_rne(v - bf16_f32(hb));
    size_t ad = (size_t)dp * D_DIM + dd;
    mh[ad] = hb;
    ml[ad] = lb;
  }
}

// =====================================================================
// Y = x.M'^T fused bias: bias[t] += sum_{d' in block} x[t,d'] * Y[t,d'].
// 3-term split. BM=BN=128, BK=32, 4 waves (2x2), per-wave 64x64,
// MFMA 32x32x16, acc[2][2]. LDS 64KB -> 2 blocks/CU.
// Triangular M': K-loop starts at kt0 = 4*nb (rows staged below d' are 0).
// =====================================================================
__global__ __launch_bounds__(256, 2) void k_y_bias(
    const unsigned short* __restrict__ xh, const unsigned short* __restrict__ xl,
    const unsigned short* __restrict__ bh, const unsigned short* __restrict__ bl,
    const float* __restrict__ xf, float* __restrict__ bias) {
  __shared__ unsigned short sAh[2][128 * 32], sAl[2][128 * 32];
  __shared__ unsigned short sBh[2][128 * 32], sBl[2][128 * 32];
  const int tid = threadIdx.x;
  const int wave = tid >> 6, lane = tid & 63;
  const int wm = wave >> 1, wn = wave & 1;
  int mb, nb;
  map_blk(blockIdx.x, mb, nb);
  const int m0 = mb * 128, n0 = nb * 128;
  const int hi32 = lane >> 5;
  const int kt0 = nb * 4;   // triangular: M' rows d' >= n0 have nonzeros at d >= n0

  const int srow0 = tid >> 2, srow1 = srow0 + 64;
  const int csrc0 = (tid & 3) ^ swz_row(srow0);
  const int csrc1 = (tid & 3) ^ swz_row(srow1);
  const size_t gaA0 = (size_t)(m0 + srow0) * D_DIM + csrc0 * 8;
  const size_t gaA1 = (size_t)(m0 + srow1) * D_DIM + csrc1 * 8;
  const size_t gaB0 = (size_t)(n0 + srow0) * D_DIM + csrc0 * 8;
  const size_t gaB1 = (size_t)(n0 + srow1) * D_DIM + csrc1 * 8;
  const int ldst0 = tid * 8, ldst1 = (tid + 256) * 8;

  f32x16 acc[2][2] = {};
  const int l31 = lane & 31;
  const int sw = swz_row(l31);
  int aoff[2][2], boff[2][2];
#pragma unroll
  for (int mi = 0; mi < 2; ++mi) {
    int r = wm * 64 + mi * 32 + l31;
#pragma unroll
    for (int kh = 0; kh < 2; ++kh)
      aoff[mi][kh] = r * 32 + (((kh * 2 + hi32) ^ sw) * 8);
  }
#pragma unroll
  for (int ni = 0; ni < 2; ++ni) {
    int r = wn * 64 + ni * 32 + l31;
#pragma unroll
    for (int kh = 0; kh < 2; ++kh)
      boff[ni][kh] = r * 32 + (((kh * 2 + hi32) ^ sw) * 8);
  }

#define Y_STAGE(t, buf)                           \
  do {                                            \
    const size_t ko = (size_t)(t) * 32;           \
    gload16(xh + gaA0 + ko, &sAh[buf][ldst0]);    \
    gload16(xh + gaA1 + ko, &sAh[buf][ldst1]);    \
    gload16(xl + gaA0 + ko, &sAl[buf][ldst0]);    \
    gload16(xl + gaA1 + ko, &sAl[buf][ldst1]);    \
    gload16(bh + gaB0 + ko, &sBh[buf][ldst0]);    \
    gload16(bh + gaB1 + ko, &sBh[buf][ldst1]);    \
    gload16(bl + gaB0 + ko, &sBl[buf][ldst0]);    \
    gload16(bl + gaB1 + ko, &sBl[buf][ldst1]);    \
  } while (0)

  Y_STAGE(kt0, 0);
  __syncthreads();
  for (int kt = kt0; kt < 32; ++kt) {
    const int cur = (kt - kt0) & 1;
    if (kt < 31) Y_STAGE(kt + 1, cur ^ 1);
#pragma unroll
    for (int kh = 0; kh < 2; ++kh) {
      bf16x8 fah[2], fal[2], fbh_[2], fbl_[2];
#pragma unroll
      for (int mi = 0; mi < 2; ++mi) {
        fah[mi] = ldfrag(&sAh[cur][aoff[mi][kh]]);
        fal[mi] = ldfrag(&sAl[cur][aoff[mi][kh]]);
      }
#pragma unroll
      for (int ni = 0; ni < 2; ++ni) {
        fbh_[ni] = ldfrag(&sBh[cur][boff[ni][kh]]);
        fbl_[ni] = ldfrag(&sBl[cur][boff[ni][kh]]);
      }
      __builtin_amdgcn_s_setprio(1);
#pragma unroll
      for (int mi = 0; mi < 2; ++mi)
#pragma unroll
        for (int ni = 0; ni < 2; ++ni) {
          acc[mi][ni] = __builtin_amdgcn_mfma_f32_32x32x16_bf16(fah[mi], fbh_[ni], acc[mi][ni], 0, 0, 0);
          acc[mi][ni] = __builtin_amdgcn_mfma_f32_32x32x16_bf16(fah[mi], fbl_[ni], acc[mi][ni], 0, 0, 0);
          acc[mi][ni] = __builtin_amdgcn_mfma_f32_32x32x16_bf16(fal[mi], fbh_[ni], acc[mi][ni], 0, 0, 0);
        }
      __builtin_amdgcn_s_setprio(0);
    }
    __syncthreads();
  }

  // bias fold: p = sum_ni x[row,col_ni] * Y_acc[ni], half-wave reduce, atomic.
#pragma unroll
  for (int mi = 0; mi < 2; ++mi)
#pragma unroll
    for (int r = 0; r < 16; ++r) {
      int row = m0 + wm * 64 + mi * 32 + (r & 3) + 8 * (r >> 2) + 4 * hi32;
      const float* xr = xf + (size_t)row * D_DIM + n0 + wn * 64 + l31;
      float p = xr[0] * acc[mi][0][r] + xr[32] * acc[mi][1][r];
      p += __shfl_xor(p, 1, 64);
      p += __shfl_xor(p, 2, 64);
      p += __shfl_xor(p, 4, 64);
      p += __shfl_xor(p, 8, 64);
      p += __shfl_xor(p, 16, 64);
      if (l31 == 0) atomicAdd(&bias[row], p);
    }
#undef Y_STAGE
}

// =====================================================================
// Q plain-bf16 GEMM with epilogue out[t,e] = S[t] * Q[t,e].
// BM=BN=128, BK=32, 4 waves (2x2), per-wave 64x64, MFMA 32x32x16.
// LDS 32KB -> 4 blocks/CU.
// =====================================================================
__global__ __launch_bounds__(256, 4) void k_q_out(
    const unsigned short* __restrict__ xh,
    const unsigned short* __restrict__ qh_,
    const float* __restrict__ S, float* __restrict__ out) {
  __shared__ unsigned short sA[2][128 * 32];
  __shared__ unsigned short sB[2][128 * 32];
  const int tid = threadIdx.x;
  const int wave = tid >> 6, lane = tid & 63;
  const int wm = wave >> 1, wn = wave & 1;
  int mb, nb;
  map_blk(blockIdx.x, mb, nb);
  const int m0 = mb * 128, n0 = nb * 128;
  const int hi32 = lane >> 5;

  const int srow0 = tid >> 2, srow1 = srow0 + 64;
  const int csrc0 = (tid & 3) ^ swz_row(srow0);
  const int csrc1 = (tid & 3) ^ swz_row(srow1);
  const size_t gaA0 = (size_t)(m0 + srow0) * D_DIM + csrc0 * 8;
  const size_t gaA1 = (size_t)(m0 + srow1) * D_DIM + csrc1 * 8;
  const size_t gaB0 = (size_t)(n0 + srow0) * D_DIM + csrc0 * 8;
  const size_t gaB1 = (size_t)(n0 + srow1) * D_DIM + csrc1 * 8;
  const int ldst0 = tid * 8, ldst1 = (tid + 256) * 8;

  f32x16 acc[2][2] = {};
  const int l31 = lane & 31;
  const int sw = swz_row(l31);
  int aoff[2][2], boff[2][2];
#pragma unroll
  for (int mi = 0; mi < 2; ++mi) {
    int r = wm * 64 + mi * 32 + l31;
#pragma unroll
    for (int kh = 0; kh < 2; ++kh)
      aoff[mi][kh] = r * 32 + (((kh * 2 + hi32) ^ sw) * 8);
  }
#pragma unroll
  for (int ni = 0; ni < 2; ++ni) {
    int r = wn * 64 + ni * 32 + l31;
#pragma unroll
    for (int kh = 0; kh < 2; ++kh)
      boff[ni][kh] = r * 32 + (((kh * 2 + hi32) ^ sw) * 8);
  }

#define Q_STAGE(t, buf)                           \
  do {                                            \
    const size_t ko = (size_t)(t) * 32;           \
    gload16(xh + gaA0 + ko, &sA[buf][ldst0]);     \
    gload16(xh + gaA1 + ko, &sA[buf][ldst1]);     \
    gload16(qh_ + gaB0 + ko, &sB[buf][ldst0]);    \
    gload16(qh_ + gaB1 + ko, &sB[buf][ldst1]);    \
  } while (0)

  Q_STAGE(0, 0);
  __syncthreads();
  for (int kt = 0; kt < 32; ++kt) {
    const int cur = kt & 1;
    if (kt < 31) Q_STAGE(kt + 1, cur ^ 1);
#pragma unroll
    for (int kh = 0; kh < 2; ++kh) {
      bf16x8 fa[2], fb[2];
#pragma unroll
      for (int mi = 0; mi < 2; ++mi) fa[mi] = ldfrag(&sA[cur][aoff[mi][kh]]);
#pragma unroll
      for (int ni = 0; ni < 2; ++ni) fb[ni] = ldfrag(&sB[cur][boff[ni][kh]]);
      __builtin_amdgcn_s_setprio(1);
#pragma unroll
      for (int mi = 0; mi < 2; ++mi)
#pragma unroll
        for (int ni = 0; ni < 2; ++ni)
          acc[mi][ni] = __builtin_amdgcn_mfma_f32_32x32x16_bf16(fa[mi], fb[ni], acc[mi][ni], 0, 0, 0);
      __builtin_amdgcn_s_setprio(0);
    }
    __syncthreads();
  }

#pragma unroll
  for (int mi = 0; mi < 2; ++mi)
#pragma unroll
    for (int r = 0; r < 16; ++r) {
      int row = m0 + wm * 64 + mi * 32 + (r & 3) + 8 * (r >> 2) + 4 * hi32;
      float sc = S[row];
      float* orow = out + (size_t)row * D_DIM + n0 + wn * 64 + l31;
      orow[0] = sc * acc[mi][0][r];
      orow[32] = sc * acc[mi][1][r];
    }
#undef Q_STAGE
}

// =====================================================================
extern "C" void kernel_launch(void* const* d_in, const int* in_sizes, int n_in,
                              void* d_out, int out_size, void* d_ws, size_t ws_size,
                              hipStream_t stream) {
  const float* x   = (const float*)d_in[0];
  const float* Wq  = (const float*)d_in[1];
  const float* Wk  = (const float*)d_in[2];
  const float* Wv  = (const float*)d_in[3];
  const float* Wih = (const float*)d_in[4];
  const float* Whh = (const float*)d_in[5];
  const float* bih = (const float*)d_in[6];
  float* out = (float*)d_out;

  char* ws = (char*)d_ws;
  size_t off = 0;
  auto alloc = [&](size_t bytes) -> char* {
    char* p = ws + off;
    off += (bytes + 255) & ~(size_t)255;
    return p;
  };
  unsigned short* xh   = (unsigned short*)alloc((size_t)M_TOK * D_DIM * 2);
  unsigned short* xl   = (unsigned short*)alloc((size_t)M_TOK * D_DIM * 2);
  unsigned short* wqh  = (unsigned short*)alloc((size_t)D_DIM * D_DIM * 2);
  unsigned short* wkth = (unsigned short*)alloc((size_t)D_DIM * D_DIM * 2);
  unsigned short* wktl = (unsigned short*)alloc((size_t)D_DIM * D_DIM * 2);
  unsigned short* wvth = (unsigned short*)alloc((size_t)D_DIM * D_DIM * 2);
  unsigned short* wvtl = (unsigned short*)alloc((size_t)D_DIM * D_DIM * 2);
  unsigned short* mph  = (unsigned short*)alloc((size_t)D_DIM * D_DIM * 2);
  unsigned short* mpl  = (unsigned short*)alloc((size_t)D_DIM * D_DIM * 2);
  float* Hf   = (float*)alloc((size_t)D_DIM * D_DIM * 4);
  float* bias = (float*)alloc((size_t)M_TOK * 4);
  float* Sbuf = (float*)alloc((size_t)M_TOK * 4);
  float* ubuf = (float*)alloc((size_t)T_DIM * 4);
  float* zbuf = (float*)alloc((size_t)T_DIM * 4);
  // Whh bf16 (8 MB) aliases wkth..wvtl (4 x 2 MB, dead after k_ht).
  unsigned short* whhb = wkth;
  (void)ws_size; (void)in_sizes; (void)n_in; (void)out_size;

  // 1. splits
  k_split<<<2048, 256, 0, stream>>>(x, M_TOK * D_DIM / 8, xh, xl);
  k_split_hi<<<512, 256, 0, stream>>>(Wq, D_DIM * D_DIM / 8, wqh);
  k_split_T<<<256, 256, 0, stream>>>(Wk, wkth, wktl);
  k_split_T<<<256, 256, 0, stream>>>(Wv, wvth, wvtl);

  // 2. zero bias accumulator and h0
  hipMemsetAsync(bias, 0, (size_t)M_TOK * 4, stream);
  hipMemsetAsync(zbuf, 0, (size_t)T_DIM * 4, stream);

  // 3. u vector
  k_u<<<T_DIM / 4, 256, 0, stream>>>(Wih, bih, ubuf);

  // 4. H[d'][d] = sum_e Wv[e,d'] Wk[e,d]  (fp32)
  k_ht<<<256, 256, 0, stream>>>(wvth, wvtl, wkth, wktl, Hf);

  // 5. M' = triangular-weighted symmetrization of H, hi/lo split
  k_nprime<<<256, 256, 0, stream>>>(Hf, mph, mpl);

  // 6. Whh -> bf16 (after k_ht: aliases the transposed weight splits)
  k_split_hi<<<1024, 256, 0, stream>>>(Whh, T_DIM * T_DIM / 8, whhb);

  // 7. Y = x.M' fused into bias = rowdot(x, Y)  (triangular K-range)
  k_y_bias<<<1024, 256, 0, stream>>>(xh, xl, mph, mpl, x, bias);

  // 8. 8-step tanh recurrence over batch rows (wave per row)
  for (int b = 0; b < B_DIM; ++b) {
    const float* hp = (b == 0) ? zbuf : (Sbuf + (size_t)(b - 1) * T_DIM);
    k_step_bf<<<T_DIM / 4, 256, 0, stream>>>(whhb, hp, ubuf, bias + (size_t)b * T_DIM,
                                             Sbuf + (size_t)b * T_DIM);
  }

  // 9. Q GEMM + scale-by-S epilogue
  k_q_out<<<1024, 256, 0, stream>>>(xh, wqh, Sbuf, out);
}

// Round 6
// 236.334 us; speedup vs baseline: 1.4433x; 1.1073x over previous
//
#include <hip/hip_runtime.h>
#include <stdint.h>

#define T_DIM 2048
#define D_DIM 1024
#define B_DIM 8
#define M_TOK (B_DIM * T_DIM)   // 16384 tokens
#define GAMMA_C 0.96875f

typedef float f32x4 __attribute__((ext_vector_type(4)));
typedef float f32x16 __attribute__((ext_vector_type(16)));
typedef float fl4 __attribute__((ext_vector_type(4)));
typedef __bf16 bf16x8 __attribute__((ext_vector_type(8)));
typedef unsigned short us8 __attribute__((ext_vector_type(8)));
typedef unsigned short us4 __attribute__((ext_vector_type(4)));

// ---------- bf16 helpers ----------
__device__ __forceinline__ unsigned short f32_bf16_rne(float f) {
  uint32_t u = __builtin_bit_cast(uint32_t, f);
  return (unsigned short)((u + 0x7FFFu + ((u >> 16) & 1u)) >> 16);
}
__device__ __forceinline__ float bf16_f32(unsigned short h) {
  uint32_t u = ((uint32_t)h) << 16;
  return __builtin_bit_cast(float, u);
}

// chunk swizzle: spreads 32-row b128 column-slice reads across bank groups
__device__ __forceinline__ int swz_row(int r) {
  return ((r >> 1) & 3) ^ ((r >> 3) & 3);
}

// ---------- global->LDS direct ----------
__device__ __forceinline__ void gload16(const void* g, void* l) {
  __builtin_amdgcn_global_load_lds(
      reinterpret_cast<const __attribute__((address_space(1))) uint32_t*>(
          reinterpret_cast<uintptr_t>(g)),
      reinterpret_cast<__attribute__((address_space(3))) uint32_t*>(
          reinterpret_cast<uintptr_t>(l)),
      16, 0, 0);
}

__device__ __forceinline__ bf16x8 ldfrag(const unsigned short* p) {
  us8 u = *reinterpret_cast<const us8*>(p);
  return __builtin_bit_cast(bf16x8, u);
}

// counted vmcnt + raw barrier (no drain)
__device__ __forceinline__ void wait_vm8_bar() {
  asm volatile("s_waitcnt vmcnt(8)" ::: "memory");
  __builtin_amdgcn_s_barrier();
}
__device__ __forceinline__ void wait_vm4_bar() {
  asm volatile("s_waitcnt vmcnt(4)" ::: "memory");
  __builtin_amdgcn_s_barrier();
}
__device__ __forceinline__ void wait_vm0_bar() {
  asm volatile("s_waitcnt vmcnt(0)" ::: "memory");
  __builtin_amdgcn_s_barrier();
}

// ---------- split f32 -> (hi, lo) bf16, 16B stores ----------
__global__ __launch_bounds__(256) void k_split(const float* __restrict__ in, int n8,
                                               unsigned short* __restrict__ hi,
                                               unsigned short* __restrict__ lo) {
  int stride = gridDim.x * blockDim.x;
  for (int i = blockIdx.x * blockDim.x + threadIdx.x; i < n8; i += stride) {
    fl4 v0 = ((const fl4*)in)[i * 2];
    fl4 v1 = ((const fl4*)in)[i * 2 + 1];
    us8 h, l;
#pragma unroll
    for (int j = 0; j < 4; ++j) {
      unsigned short hb = f32_bf16_rne(v0[j]);
      h[j] = hb;
      l[j] = f32_bf16_rne(v0[j] - bf16_f32(hb));
      unsigned short hb1 = f32_bf16_rne(v1[j]);
      h[j + 4] = hb1;
      l[j + 4] = f32_bf16_rne(v1[j] - bf16_f32(hb1));
    }
    ((us8*)hi)[i] = h;
    ((us8*)lo)[i] = l;
  }
}

__global__ __launch_bounds__(256) void k_split_hi(const float* __restrict__ in, int n8,
                                                  unsigned short* __restrict__ hi) {
  int stride = gridDim.x * blockDim.x;
  for (int i = blockIdx.x * blockDim.x + threadIdx.x; i < n8; i += stride) {
    fl4 v0 = ((const fl4*)in)[i * 2];
    fl4 v1 = ((const fl4*)in)[i * 2 + 1];
    us8 h;
#pragma unroll
    for (int j = 0; j < 4; ++j) {
      h[j] = f32_bf16_rne(v0[j]);
      h[j + 4] = f32_bf16_rne(v1[j]);
    }
    ((us8*)hi)[i] = h;
  }
}

// ---------- transpose-split: out_t[d][e] = split(in[e][d]), 64x64 tiles ----------
__global__ __launch_bounds__(256) void k_split_T(const float* __restrict__ in,
                                                 unsigned short* __restrict__ th,
                                                 unsigned short* __restrict__ tl) {
  __shared__ float tile[64][69];
  int be = blockIdx.x >> 4, bd = blockIdx.x & 15;
  int e0 = be * 64, d0 = bd * 64;
  int r = threadIdx.x >> 4;
  int c = (threadIdx.x & 15) * 4;
#pragma unroll
  for (int it = 0; it < 4; ++it) {
    int rr = r + it * 16;
    fl4 v = *(const fl4*)(in + (size_t)(e0 + rr) * D_DIM + d0 + c);
#pragma unroll
    for (int j = 0; j < 4; ++j) tile[rr][c + j] = v[j];
  }
  __syncthreads();
#pragma unroll
  for (int it = 0; it < 4; ++it) {
    int dr = r + it * 16;
    us4 h, l;
#pragma unroll
    for (int j = 0; j < 4; ++j) {
      float f = tile[c + j][dr];
      h[j] = f32_bf16_rne(f);
      l[j] = f32_bf16_rne(f - bf16_f32(h[j]));
    }
    *(us4*)(th + (size_t)(d0 + dr) * D_DIM + e0 + c) = h;
    *(us4*)(tl + (size_t)(d0 + dr) * D_DIM + e0 + c) = l;
  }
}

// ---------- u[t] = GAMMA * rowsum(W_ih[t,:]) + b_ih[t] ----------
__global__ __launch_bounds__(256) void k_u(const float* __restrict__ Wih,
                                           const float* __restrict__ bih,
                                           float* __restrict__ u) {
  int wave = threadIdx.x >> 6, lane = threadIdx.x & 63;
  int t = blockIdx.x * 4 + wave;
  const fl4* row = (const fl4*)(Wih + (size_t)t * T_DIM);
  float s = 0.f;
#pragma unroll
  for (int i = 0; i < 8; ++i) {
    fl4 v = row[lane + i * 64];
    s += v[0] + v[1] + v[2] + v[3];
  }
#pragma unroll
  for (int m = 32; m >= 1; m >>= 1) s += __shfl_xor(s, m, 64);
  if (lane == 0) u[t] = GAMMA_C * s + bih[t];
}

// ---------- h_out[t] = tanh(u[t] + dot(Whh_bf16[t,:], h_prev) + bias_row[t]) ----------
__global__ __launch_bounds__(256) void k_step_bf(const unsigned short* __restrict__ Whh_b,
                                                 const float* __restrict__ hprev,
                                                 const float* __restrict__ u,
                                                 const float* __restrict__ biasrow,
                                                 float* __restrict__ hout) {
  int wave = threadIdx.x >> 6, lane = threadIdx.x & 63;
  int t = blockIdx.x * 4 + wave;
  const unsigned short* row = Whh_b + (size_t)t * T_DIM;
  float s = 0.f;
#pragma unroll
  for (int i = 0; i < 4; ++i) {
    us8 w = *(const us8*)(row + i * 512 + lane * 8);
    fl4 h0 = *(const fl4*)(hprev + i * 512 + lane * 8);
    fl4 h1 = *(const fl4*)(hprev + i * 512 + lane * 8 + 4);
    s += bf16_f32(w[0]) * h0[0] + bf16_f32(w[1]) * h0[1] +
         bf16_f32(w[2]) * h0[2] + bf16_f32(w[3]) * h0[3] +
         bf16_f32(w[4]) * h1[0] + bf16_f32(w[5]) * h1[1] +
         bf16_f32(w[6]) * h1[2] + bf16_f32(w[7]) * h1[3];
  }
#pragma unroll
  for (int m = 32; m >= 1; m >>= 1) s += __shfl_xor(s, m, 64);
  if (lane == 0) hout[t] = tanhf(u[t] + s + biasrow[t]);
}

// =====================================================================
// H[d'][d] = sum_e Wv[e,d'] * Wk[e,d], 3-term split, fp32 output.
// 64x64 tiles, 4 waves (2x2), MFMA 32x32x16, no-drain schedule.
// =====================================================================
__global__ __launch_bounds__(256) void k_ht(
    const unsigned short* __restrict__ ah, const unsigned short* __restrict__ al,
    const unsigned short* __restrict__ bh, const unsigned short* __restrict__ bl,
    float* __restrict__ Hf) {
  __shared__ unsigned short sAh[2][64 * 32], sAl[2][64 * 32];
  __shared__ unsigned short sBh[2][64 * 32], sBl[2][64 * 32];
  const int tid = threadIdx.x;
  const int wave = tid >> 6, lane = tid & 63;
  const int wm = wave >> 1, wn = wave & 1;
  const int m0 = (blockIdx.x >> 4) * 64, n0 = (blockIdx.x & 15) * 64;
  const int hi32 = lane >> 5;

  const int srow = tid >> 2;
  const int csrc = (tid & 3) ^ swz_row(srow);
  const size_t ga = (size_t)(m0 + srow) * D_DIM + csrc * 8;
  const size_t gb = (size_t)(n0 + srow) * D_DIM + csrc * 8;
  const int ldst = tid * 8;

  f32x16 acc = {};
  const int l31 = lane & 31;
  const int sw = swz_row(l31);
  const int ar = wm * 32 + l31;
  const int br = wn * 32 + l31;
  int aoff[2], boff[2];
#pragma unroll
  for (int kh = 0; kh < 2; ++kh) {
    aoff[kh] = ar * 32 + (((kh * 2 + hi32) ^ sw) * 8);
    boff[kh] = br * 32 + (((kh * 2 + hi32) ^ sw) * 8);
  }

  auto stage = [&](int t, int buf) {
    const size_t ko = (size_t)t * 32;
    gload16(ah + ga + ko, &sAh[buf][ldst]);
    gload16(al + ga + ko, &sAl[buf][ldst]);
    gload16(bh + gb + ko, &sBh[buf][ldst]);
    gload16(bl + gb + ko, &sBl[buf][ldst]);
  };

  stage(0, 0);
  stage(1, 1);
  for (int kt = 0; kt < 32; ++kt) {
    const int cur = kt & 1;
    if (kt < 31) wait_vm4_bar(); else wait_vm0_bar();
#pragma unroll
    for (int kh = 0; kh < 2; ++kh) {
      bf16x8 fah = ldfrag(&sAh[cur][aoff[kh]]);
      bf16x8 fal = ldfrag(&sAl[cur][aoff[kh]]);
      bf16x8 fbh = ldfrag(&sBh[cur][boff[kh]]);
      bf16x8 fbl = ldfrag(&sBl[cur][boff[kh]]);
      acc = __builtin_amdgcn_mfma_f32_32x32x16_bf16(fah, fbh, acc, 0, 0, 0);
      acc = __builtin_amdgcn_mfma_f32_32x32x16_bf16(fah, fbl, acc, 0, 0, 0);
      acc = __builtin_amdgcn_mfma_f32_32x32x16_bf16(fal, fbh, acc, 0, 0, 0);
    }
    __builtin_amdgcn_s_barrier();
    if (kt + 2 <= 31) stage(kt + 2, cur);
  }
#pragma unroll
  for (int r = 0; r < 16; ++r) {
    int row = m0 + wm * 32 + (r & 3) + 8 * (r >> 2) + 4 * hi32;
    int col = n0 + wn * 32 + l31;
    Hf[(size_t)row * D_DIM + col] = acc[r];
  }
}

// =====================================================================
// M'[d'][d] = H[d',d]+H[d,d'] (d>d'); H[d,d] (d==d'); 0 (d<d').
// =====================================================================
__global__ __launch_bounds__(256) void k_nprime(const float* __restrict__ Hf,
                                                unsigned short* __restrict__ mh,
                                                unsigned short* __restrict__ ml) {
  __shared__ float t2[64][65];
  const int ti = blockIdx.x >> 4;   // d' tile
  const int tj = blockIdx.x & 15;   // d  tile
  const int r0 = ti * 64, c0 = tj * 64;
  const int a = threadIdx.x >> 2;
  const int b4 = (threadIdx.x & 3) * 16;
  if (tj < ti) {
#pragma unroll
    for (int j = 0; j < 16; ++j) {
      size_t ad = (size_t)(r0 + a) * D_DIM + c0 + b4 + j;
      mh[ad] = 0;
      ml[ad] = 0;
    }
    return;
  }
#pragma unroll
  for (int j = 0; j < 16; j += 4) {
    fl4 v = *(const fl4*)(Hf + (size_t)(c0 + a) * D_DIM + r0 + b4 + j);
#pragma unroll
    for (int q = 0; q < 4; ++q) t2[a][b4 + j + q] = v[q];
  }
  __syncthreads();
#pragma unroll
  for (int j = 0; j < 16; ++j) {
    int dp = r0 + a;
    int dd = c0 + b4 + j;
    float v = 0.f;
    if (dd > dp)       v = Hf[(size_t)dp * D_DIM + dd] + t2[b4 + j][a];
    else if (dd == dp) v = Hf[(size_t)dp * D_DIM + dd];
    unsigned short hb = f32_bf16_rne(v);
    unsigned short lb = f32_bf16_rne(v - bf16_f32(hb));
    size_t ad = (size_t)dp * D_DIM + dd;
    mh[ad] = hb;
    ml[ad] = lb;
  }
}

// =====================================================================
// Y = x.M'^T fused bias. 512 blocks, each handles N-tile pair {np, 7-np}
// (triangular K-ranges sum to a uniform 36 kt/block -> one dispatch round).
// BM=BN=128, BK=32, 4 waves (2x2), per-wave 64x64, MFMA 32x32x16.
// No-drain schedule: counted vmcnt(8) + raw barriers, stage kt+2 after
// the post-compute barrier. LDS 64KB -> 2 blocks/CU.
// Epilogue x read from L2-warm xh+xl (exact to 2^-16), not cold fp32.
// =====================================================================
__global__ __launch_bounds__(256, 2) void k_y_bias(
    const unsigned short* __restrict__ xh, const unsigned short* __restrict__ xl,
    const unsigned short* __restrict__ bh, const unsigned short* __restrict__ bl,
    float* __restrict__ bias) {
  __shared__ unsigned short sAh[2][128 * 32], sAl[2][128 * 32];
  __shared__ unsigned short sBh[2][128 * 32], sBl[2][128 * 32];
  const int tid = threadIdx.x;
  const int wave = tid >> 6, lane = tid & 63;
  const int wm = wave >> 1, wn = wave & 1;
  // 512 blocks: 64/XCD; 4 consecutive same-XCD blocks share the m-strip.
  const int xcd = blockIdx.x & 7, seq = blockIdx.x >> 3;
  const int mb = xcd * 16 + (seq >> 2);
  const int np = seq & 3;
  const int m0 = mb * 128;
  const int hi32 = lane >> 5;

  const int srow0 = tid >> 2, srow1 = srow0 + 64;
  const int csrc0 = (tid & 3) ^ swz_row(srow0);
  const int csrc1 = (tid & 3) ^ swz_row(srow1);
  const size_t gaA0 = (size_t)(m0 + srow0) * D_DIM + csrc0 * 8;
  const size_t gaA1 = (size_t)(m0 + srow1) * D_DIM + csrc1 * 8;
  const int ldst0 = tid * 8, ldst1 = (tid + 256) * 8;

  const int l31 = lane & 31;
  const int sw = swz_row(l31);
  int aoff[2][2], boff[2][2];
#pragma unroll
  for (int mi = 0; mi < 2; ++mi) {
    int r = wm * 64 + mi * 32 + l31;
#pragma unroll
    for (int kh = 0; kh < 2; ++kh)
      aoff[mi][kh] = r * 32 + (((kh * 2 + hi32) ^ sw) * 8);
  }
#pragma unroll
  for (int ni = 0; ni < 2; ++ni) {
    int r = wn * 64 + ni * 32 + l31;
#pragma unroll
    for (int kh = 0; kh < 2; ++kh)
      boff[ni][kh] = r * 32 + (((kh * 2 + hi32) ^ sw) * 8);
  }

  auto run_phase = [&](int nb) {
    const int n0 = nb * 128;
    const int kt0 = nb * 4;
    const size_t gB0 = (size_t)(n0 + srow0) * D_DIM + csrc0 * 8;
    const size_t gB1 = (size_t)(n0 + srow1) * D_DIM + csrc1 * 8;

    auto stage = [&](int t, int buf) {
      const size_t ko = (size_t)t * 32;
      gload16(xh + gaA0 + ko, &sAh[buf][ldst0]);
      gload16(xh + gaA1 + ko, &sAh[buf][ldst1]);
      gload16(xl + gaA0 + ko, &sAl[buf][ldst0]);
      gload16(xl + gaA1 + ko, &sAl[buf][ldst1]);
      gload16(bh + gB0 + ko, &sBh[buf][ldst0]);
      gload16(bh + gB1 + ko, &sBh[buf][ldst1]);
      gload16(bl + gB0 + ko, &sBl[buf][ldst0]);
      gload16(bl + gB1 + ko, &sBl[buf][ldst1]);
    };

    f32x16 acc[2][2] = {};
    stage(kt0, 0);
    stage(kt0 + 1, 1);
    for (int kt = kt0; kt < 32; ++kt) {
      const int cur = (kt - kt0) & 1;
      if (kt < 31) wait_vm8_bar(); else wait_vm0_bar();
#pragma unroll
      for (int kh = 0; kh < 2; ++kh) {
        bf16x8 fah[2], fal[2], fbh_[2], fbl_[2];
#pragma unroll
        for (int mi = 0; mi < 2; ++mi) {
          fah[mi] = ldfrag(&sAh[cur][aoff[mi][kh]]);
          fal[mi] = ldfrag(&sAl[cur][aoff[mi][kh]]);
        }
#pragma unroll
        for (int ni = 0; ni < 2; ++ni) {
          fbh_[ni] = ldfrag(&sBh[cur][boff[ni][kh]]);
          fbl_[ni] = ldfrag(&sBl[cur][boff[ni][kh]]);
        }
        __builtin_amdgcn_s_setprio(1);
#pragma unroll
        for (int mi = 0; mi < 2; ++mi)
#pragma unroll
          for (int ni = 0; ni < 2; ++ni) {
            acc[mi][ni] = __builtin_amdgcn_mfma_f32_32x32x16_bf16(fah[mi], fbh_[ni], acc[mi][ni], 0, 0, 0);
            acc[mi][ni] = __builtin_amdgcn_mfma_f32_32x32x16_bf16(fah[mi], fbl_[ni], acc[mi][ni], 0, 0, 0);
            acc[mi][ni] = __builtin_amdgcn_mfma_f32_32x32x16_bf16(fal[mi], fbh_[ni], acc[mi][ni], 0, 0, 0);
          }
        __builtin_amdgcn_s_setprio(0);
      }
      __builtin_amdgcn_s_barrier();
      if (kt + 2 <= 31) stage(kt + 2, cur);
    }

    // bias fold: p = sum_ni x[row, col_ni] * Y_acc[ni]; x from L2-warm xh+xl.
#pragma unroll
    for (int mi = 0; mi < 2; ++mi)
#pragma unroll
      for (int r = 0; r < 16; ++r) {
        int row = m0 + wm * 64 + mi * 32 + (r & 3) + 8 * (r >> 2) + 4 * hi32;
        size_t ix = (size_t)row * D_DIM + n0 + wn * 64 + l31;
        float xv0 = bf16_f32(xh[ix]) + bf16_f32(xl[ix]);
        float xv1 = bf16_f32(xh[ix + 32]) + bf16_f32(xl[ix + 32]);
        float p = xv0 * acc[mi][0][r] + xv1 * acc[mi][1][r];
        p += __shfl_xor(p, 1, 64);
        p += __shfl_xor(p, 2, 64);
        p += __shfl_xor(p, 4, 64);
        p += __shfl_xor(p, 8, 64);
        p += __shfl_xor(p, 16, 64);
        if (l31 == 0) atomicAdd(&bias[row], p);
      }
  };

  run_phase(np);
  run_phase(7 - np);
}

// =====================================================================
// Q plain-bf16 GEMM with epilogue out[t,e] = S[t] * Q[t,e].
// BM=BN=128, BK=32, 4 waves (2x2), per-wave 64x64, no-drain schedule.
// =====================================================================
__global__ __launch_bounds__(256, 4) void k_q_out(
    const unsigned short* __restrict__ xh,
    const unsigned short* __restrict__ qh_,
    const float* __restrict__ S, float* __restrict__ out) {
  __shared__ unsigned short sA[2][128 * 32];
  __shared__ unsigned short sB[2][128 * 32];
  const int tid = threadIdx.x;
  const int wave = tid >> 6, lane = tid & 63;
  const int wm = wave >> 1, wn = wave & 1;
  int sw0 = (blockIdx.x & 7) * 128 + (blockIdx.x >> 3);
  const int mb = sw0 >> 3, nb = sw0 & 7;
  const int m0 = mb * 128, n0 = nb * 128;
  const int hi32 = lane >> 5;

  const int srow0 = tid >> 2, srow1 = srow0 + 64;
  const int csrc0 = (tid & 3) ^ swz_row(srow0);
  const int csrc1 = (tid & 3) ^ swz_row(srow1);
  const size_t gaA0 = (size_t)(m0 + srow0) * D_DIM + csrc0 * 8;
  const size_t gaA1 = (size_t)(m0 + srow1) * D_DIM + csrc1 * 8;
  const size_t gaB0 = (size_t)(n0 + srow0) * D_DIM + csrc0 * 8;
  const size_t gaB1 = (size_t)(n0 + srow1) * D_DIM + csrc1 * 8;
  const int ldst0 = tid * 8, ldst1 = (tid + 256) * 8;

  f32x16 acc[2][2] = {};
  const int l31 = lane & 31;
  const int sw = swz_row(l31);
  int aoff[2][2], boff[2][2];
#pragma unroll
  for (int mi = 0; mi < 2; ++mi) {
    int r = wm * 64 + mi * 32 + l31;
#pragma unroll
    for (int kh = 0; kh < 2; ++kh)
      aoff[mi][kh] = r * 32 + (((kh * 2 + hi32) ^ sw) * 8);
  }
#pragma unroll
  for (int ni = 0; ni < 2; ++ni) {
    int r = wn * 64 + ni * 32 + l31;
#pragma unroll
    for (int kh = 0; kh < 2; ++kh)
      boff[ni][kh] = r * 32 + (((kh * 2 + hi32) ^ sw) * 8);
  }

  auto stage = [&](int t, int buf) {
    const size_t ko = (size_t)t * 32;
    gload16(xh + gaA0 + ko, &sA[buf][ldst0]);
    gload16(xh + gaA1 + ko, &sA[buf][ldst1]);
    gload16(qh_ + gaB0 + ko, &sB[buf][ldst0]);
    gload16(qh_ + gaB1 + ko, &sB[buf][ldst1]);
  };

  stage(0, 0);
  stage(1, 1);
  for (int kt = 0; kt < 32; ++kt) {
    const int cur = kt & 1;
    if (kt < 31) wait_vm4_bar(); else wait_vm0_bar();
#pragma unroll
    for (int kh = 0; kh < 2; ++kh) {
      bf16x8 fa[2], fb[2];
#pragma unroll
      for (int mi = 0; mi < 2; ++mi) fa[mi] = ldfrag(&sA[cur][aoff[mi][kh]]);
#pragma unroll
      for (int ni = 0; ni < 2; ++ni) fb[ni] = ldfrag(&sB[cur][boff[ni][kh]]);
      __builtin_amdgcn_s_setprio(1);
#pragma unroll
      for (int mi = 0; mi < 2; ++mi)
#pragma unroll
        for (int ni = 0; ni < 2; ++ni)
          acc[mi][ni] = __builtin_amdgcn_mfma_f32_32x32x16_bf16(fa[mi], fb[ni], acc[mi][ni], 0, 0, 0);
      __builtin_amdgcn_s_setprio(0);
    }
    __builtin_amdgcn_s_barrier();
    if (kt + 2 <= 31) stage(kt + 2, cur);
  }

#pragma unroll
  for (int mi = 0; mi < 2; ++mi)
#pragma unroll
    for (int r = 0; r < 16; ++r) {
      int row = m0 + wm * 64 + mi * 32 + (r & 3) + 8 * (r >> 2) + 4 * hi32;
      float sc = S[row];
      float* orow = out + (size_t)row * D_DIM + n0 + wn * 64 + l31;
      orow[0] = sc * acc[mi][0][r];
      orow[32] = sc * acc[mi][1][r];
    }
}

// =====================================================================
extern "C" void kernel_launch(void* const* d_in, const int* in_sizes, int n_in,
                              void* d_out, int out_size, void* d_ws, size_t ws_size,
                              hipStream_t stream) {
  const float* x   = (const float*)d_in[0];
  const float* Wq  = (const float*)d_in[1];
  const float* Wk  = (const float*)d_in[2];
  const float* Wv  = (const float*)d_in[3];
  const float* Wih = (const float*)d_in[4];
  const float* Whh = (const float*)d_in[5];
  const float* bih = (const float*)d_in[6];
  float* out = (float*)d_out;

  char* ws = (char*)d_ws;
  size_t off = 0;
  auto alloc = [&](size_t bytes) -> char* {
    char* p = ws + off;
    off += (bytes + 255) & ~(size_t)255;
    return p;
  };
  unsigned short* xh   = (unsigned short*)alloc((size_t)M_TOK * D_DIM * 2);
  unsigned short* xl   = (unsigned short*)alloc((size_t)M_TOK * D_DIM * 2);
  unsigned short* wqh  = (unsigned short*)alloc((size_t)D_DIM * D_DIM * 2);
  unsigned short* wkth = (unsigned short*)alloc((size_t)D_DIM * D_DIM * 2);
  unsigned short* wktl = (unsigned short*)alloc((size_t)D_DIM * D_DIM * 2);
  unsigned short* wvth = (unsigned short*)alloc((size_t)D_DIM * D_DIM * 2);
  unsigned short* wvtl = (unsigned short*)alloc((size_t)D_DIM * D_DIM * 2);
  unsigned short* mph  = (unsigned short*)alloc((size_t)D_DIM * D_DIM * 2);
  unsigned short* mpl  = (unsigned short*)alloc((size_t)D_DIM * D_DIM * 2);
  float* Hf   = (float*)alloc((size_t)D_DIM * D_DIM * 4);
  float* bias = (float*)alloc((size_t)M_TOK * 4);
  float* Sbuf = (float*)alloc((size_t)M_TOK * 4);
  float* ubuf = (float*)alloc((size_t)T_DIM * 4);
  float* zbuf = (float*)alloc((size_t)T_DIM * 4);
  // Whh bf16 (8 MB) aliases wkth..wvtl (4 x 2 MB, dead after k_ht).
  unsigned short* whhb = wkth;
  (void)ws_size; (void)in_sizes; (void)n_in; (void)out_size;

  // 1. splits
  k_split<<<2048, 256, 0, stream>>>(x, M_TOK * D_DIM / 8, xh, xl);
  k_split_hi<<<512, 256, 0, stream>>>(Wq, D_DIM * D_DIM / 8, wqh);
  k_split_T<<<256, 256, 0, stream>>>(Wk, wkth, wktl);
  k_split_T<<<256, 256, 0, stream>>>(Wv, wvth, wvtl);

  // 2. zero bias accumulator and h0
  hipMemsetAsync(bias, 0, (size_t)M_TOK * 4, stream);
  hipMemsetAsync(zbuf, 0, (size_t)T_DIM * 4, stream);

  // 3. u vector
  k_u<<<T_DIM / 4, 256, 0, stream>>>(Wih, bih, ubuf);

  // 4. H[d'][d] = sum_e Wv[e,d'] Wk[e,d]  (fp32)
  k_ht<<<256, 256, 0, stream>>>(wvth, wvtl, wkth, wktl, Hf);

  // 5. M' = triangular-weighted symmetrization of H, hi/lo split
  k_nprime<<<256, 256, 0, stream>>>(Hf, mph, mpl);

  // 6. Whh -> bf16 (after k_ht: aliases the transposed weight splits)
  k_split_hi<<<1024, 256, 0, stream>>>(Whh, T_DIM * T_DIM / 8, whhb);

  // 7. Y = x.M' fused into bias = rowdot(x, Y)  (paired triangular grid)
  k_y_bias<<<512, 256, 0, stream>>>(xh, xl, mph, mpl, bias);

  // 8. 8-step tanh recurrence over batch rows (wave per row)
  for (int b = 0; b < B_DIM; ++b) {
    const float* hp = (b == 0) ? zbuf : (Sbuf + (size_t)(b - 1) * T_DIM);
    k_step_bf<<<T_DIM / 4, 256, 0, stream>>>(whhb, hp, ubuf, bias + (size_t)b * T_DIM,
                                             Sbuf + (size_t)b * T_DIM);
  }

  // 9. Q GEMM + scale-by-S epilogue
  k_q_out<<<1024, 256, 0, stream>>>(xh, wqh, Sbuf, out);
}